// Round 1
// baseline (363.359 us; speedup 1.0000x reference)
//
#include <hip/hip_runtime.h>

#define BB 256
#define SS 200
#define MM 32
#define KDIM 128
#define VDIM 256
#define QDIM 128
#define HH 64
#define NROWS 10001
#define NSAMP (BB*SS)
#define INDIM (VDIM+QDIM)
#define DHS 8192
#define DHMASK (DHS-1)
#define XR 16
#define NB_ATTN 2501

typedef unsigned long long u64;
typedef unsigned int u32;

__device__ __forceinline__ float fexp(float x){ return __builtin_amdgcn_exp2f(x * 1.44269504f); }
__device__ __forceinline__ float fsigm(float x){ return __builtin_amdgcn_rcpf(1.f + fexp(-x)); }
__device__ __forceinline__ float ftanh(float x){ return 1.f - 2.f*__builtin_amdgcn_rcpf(1.f + fexp(2.f*x)); }
__device__ __forceinline__ int clampq(int q){ return q < 0 ? 0 : (q > NROWS-1 ? NROWS-1 : q); }

__device__ __forceinline__ u32 hash64(u64 x){
  x ^= x >> 33; x *= 0xff51afd7ed558ccdULL;
  x ^= x >> 33; x *= 0xc4ceb9fe1a85ec53ULL;
  x ^= x >> 33;
  return (u32)x;
}

__device__ __forceinline__ u64 shflx64(u64 v, int m){
  int lo = __shfl_xor((int)(u32)v, m, 64);
  int hi = __shfl_xor((int)(u32)(v >> 32), m, 64);
  return ((u64)(u32)hi << 32) | (u32)lo;
}

// transposes + present init:
// WQT4[(d4*256+j)*4+dd]=W_ih[j][VDIM+4d4+dd]; KT[d*32+m]=key_mem[m][d];
// WVT[v*256+j]=W_ih[j][v]; present[:]=0
__global__ void k_tr(const float* __restrict__ W_ih, const float* __restrict__ key_mem,
                     float* __restrict__ WQT4, float* __restrict__ KT,
                     float* __restrict__ WVT, u32* __restrict__ present){
  int idx = blockIdx.x*256 + threadIdx.x;
  if (idx < 131072) {
    int dd = idx & 3, j = (idx >> 2) & 255, d4 = idx >> 10;
    WQT4[idx] = W_ih[j*INDIM + VDIM + 4*d4 + dd];
  } else if (idx < 135168) {
    int t = idx - 131072;
    int m = t & 31, d = t >> 5; KT[t] = key_mem[m*KDIM + d];
  } else if (idx < 200704) {
    int t = idx - 135168;
    int j = t & 255, v = t >> 8; WVT[v*256 + j] = W_ih[j*INDIM + v];
  } else {
    int t = idx - 200704;
    if (t < NROWS) present[t] = 0u;
  }
}

// fused front: blocks [0,2501) attn ; [2501,2533) vw ; [2533,2733) mark
__global__ __launch_bounds__(256) void k_front(
    const float* __restrict__ emb, const float* __restrict__ KT,
    const float* __restrict__ val, const float* __restrict__ WVT,
    const int* __restrict__ q_data,
    float* __restrict__ CW, u64* __restrict__ KEYT,
    float* __restrict__ VW, u32* __restrict__ present){
  int bid = blockIdx.x;
  if (bid < NB_ATTN) {
    // ---- attn: one wave per row ----
    int w = threadIdx.x >> 6, l = threadIdx.x & 63;
    int n = bid*4 + w;
    __shared__ float se[4][QDIM];
    bool valid = (n < NROWS);
    if (valid) {
      se[w][l]      = emb[n*QDIM + l];
      se[w][l + 64] = emb[n*QDIM + l + 64];
    }
    __syncthreads();
    int m = l & 31;
    float logit = 0.f;
    if (valid && l < 32)
      for (int d = 0; d < KDIM; ++d) logit += se[w][d] * KT[d*32 + m];
    float mx = logit;
    #pragma unroll
    for (int msk = 16; msk >= 1; msk >>= 1) mx = fmaxf(mx, __shfl_xor(mx, msk, 64));
    float e = (l < 32) ? expf(logit - mx) : 0.f;    // precise expf: trit boundaries
    float sum = e;
    #pragma unroll
    for (int msk = 16; msk >= 1; msk >>= 1) sum += __shfl_xor(sum, msk, 64);
    float cw = e / sum;
    float wv = fminf((cw - 0.075f)/0.013f, (1.0f - cw)/0.912f);
    wv = fmaxf(wv, 0.f);
    int iv = (wv >= 0.6f) ? 2 : ((wv >= 0.1f) ? 1 : 0);
    int ee = (m < 16) ? m + 16 : m - 16;   // key = kh*3^16 + kl (reference packing)
    u64 p3 = 1;
    for (int i = 0; i < 31; ++i) if (i < ee) p3 *= 3ULL;
    u64 term = (valid && l < 32) ? (u64)iv * p3 : 0ULL;
    #pragma unroll
    for (int msk = 16; msk >= 1; msk >>= 1) term += shflx64(term, msk);
    if (valid && l < 32) CW[n*256 + m] = cw;
    if (valid && l == 0) KEYT[n] = term;
  } else if (bid < NB_ATTN + MM) {
    // ---- vw: VW[m][j] = sum_v val[m][v]*WVT[v][j] ----
    int m = bid - NB_ATTN, j = threadIdx.x;
    __shared__ float sval[VDIM];
    sval[j] = val[m*VDIM + j];
    __syncthreads();
    float a0=0.f, a1=0.f, a2=0.f, a3=0.f;
    for (int v = 0; v < VDIM; v += 4) {
      a0 += sval[v+0]*WVT[(v+0)*256 + j];
      a1 += sval[v+1]*WVT[(v+1)*256 + j];
      a2 += sval[v+2]*WVT[(v+2)*256 + j];
      a3 += sval[v+3]*WVT[(v+3)*256 + j];
    }
    VW[m*256 + j] = (a0+a1)+(a2+a3);
  } else {
    // ---- mark ----
    int i = (bid - NB_ATTN - MM)*256 + threadIdx.x;
    if (i < NSAMP) present[clampq(q_data[i])] = 1u;
  }
}

// XW4 row = bias + cw.VW + emb.WqT: 16 rows/block tiled GEMM
__global__ __launch_bounds__(256) void k_xw(
    const float* __restrict__ CW, const float* __restrict__ emb,
    const float* __restrict__ VW, const float* __restrict__ WQT4,
    const float* __restrict__ b_ih, const float* __restrict__ b_hh,
    float* __restrict__ XW4){
  int base = blockIdx.x * XR;
  int j = threadIdx.x;
  __shared__ float scw[XR][32];
  __shared__ __align__(16) float ses[XR][QDIM];
  for (int idx = j; idx < XR*32; idx += 256) {
    int r = idx >> 5, m = idx & 31, n = base + r;
    scw[r][m] = (n < NROWS) ? CW[n*256 + m] : 0.f;
  }
  for (int idx = j; idx < XR*QDIM; idx += 256) {
    int r = idx >> 7, d = idx & 127, n = base + r;
    ses[r][d] = (n < NROWS) ? emb[n*QDIM + d] : 0.f;
  }
  __syncthreads();
  float bias = b_ih[j] + b_hh[j];
  float acc[XR];
  #pragma unroll
  for (int r = 0; r < XR; ++r) acc[r] = bias;
  for (int m = 0; m < MM; ++m) {
    float wv = VW[m*256 + j];
    #pragma unroll
    for (int r = 0; r < XR; ++r) acc[r] += scw[r][m] * wv;
  }
  for (int d4 = 0; d4 < QDIM/4; ++d4) {
    float4 wq = *(const float4*)(WQT4 + d4*1024 + j*4);
    #pragma unroll
    for (int r = 0; r < XR; ++r) {
      float4 ev = *(const float4*)(&ses[r][4*d4]);
      acc[r] += ev.x*wq.x + ev.y*wq.y + ev.z*wq.z + ev.w*wq.w;
    }
  }
  int gate = j >> 6, unit = j & 63;
  #pragma unroll
  for (int r = 0; r < XR; ++r)
    if (base + r < NROWS) XW4[(size_t)(base + r)*256 + 4*unit + gate] = acc[r];
}

__global__ __launch_bounds__(1024) void k_dedup(
    const u32* __restrict__ present, const u64* __restrict__ KEYT,
    u32* __restrict__ g_htab, u32* __restrict__ g_pay,
    u32* __restrict__ counter, u64* __restrict__ uniq){
  __shared__ u32 sh_tab[DHS];
  __shared__ u32 sh_pay[DHS];
  __shared__ u32 sh_cnt;
  int tid = threadIdx.x;
  for (int i = tid; i < DHS; i += 1024) sh_tab[i] = 0u;
  if (tid == 0) sh_cnt = 0u;
  __syncthreads();
  for (int n = tid; n < NROWS; n += 1024) {
    if (present[n] != 1u) continue;
    u64 key = KEYT[n];
    u32 h = hash64(key) & DHMASK;
    while (true) {
      u32 cur = sh_tab[h];
      if (cur != 0u) {
        if (KEYT[cur-1u] == key) break;
        h = (h + 1) & DHMASK; continue;
      }
      u32 prev = atomicCAS(&sh_tab[h], 0u, (u32)(n + 1));
      if (prev == 0u) {
        u32 idx = atomicAdd(&sh_cnt, 1u);
        uniq[idx] = key;
        sh_pay[h] = idx;
        break;
      }
      if (KEYT[prev-1u] == key) break;
      h = (h + 1) & DHMASK;
    }
  }
  __syncthreads();
  for (int i = tid; i < DHS; i += 1024) {
    u32 v = sh_tab[i];
    g_htab[i] = v;
    g_pay[i]  = v ? sh_pay[i] : 0u;
  }
  if (tid == 0) *counter = sh_cnt;
}

__global__ __launch_bounds__(256) void k_rank(const u64* __restrict__ uniq,
                                              const u32* __restrict__ counter,
                                              u32* __restrict__ RANK){
  __shared__ u64 chunk[2048];
  u32 U = *counter;
  int u = blockIdx.x*256 + threadIdx.x;
  u64 mykey = (u < (int)U) ? uniq[u] : 0;
  u32 cnt = 0;
  for (u32 base = 0; base < U; base += 2048) {
    u32 n = (U - base < 2048u) ? (U - base) : 2048u;
    __syncthreads();
    for (u32 t = threadIdx.x; t < n; t += 256) chunk[t] = uniq[base + t];
    __syncthreads();
    if (u < (int)U)
      for (u32 j = 0; j < n; ++j) cnt += (chunk[j] < mykey) ? 1u : 0u;
  }
  if (u < (int)U) RANK[u] = cnt;
}

__global__ void k_qrank(const u32* __restrict__ present, const u64* __restrict__ KEYT,
                        const u32* __restrict__ g_htab, const u32* __restrict__ g_pay,
                        const u32* __restrict__ RANK, u32* __restrict__ RANKQ){
  int n = blockIdx.x*blockDim.x + threadIdx.x;
  if (n >= NROWS || present[n] != 1u) return;
  u64 key = KEYT[n];
  u32 h = hash64(key) & DHMASK;
  while (true) {
    u32 cur = g_htab[h];
    if (cur != 0u && KEYT[cur-1u] == key) { RANKQ[n] = RANK[g_pay[h]]; return; }
    h = (h + 1) & DHMASK;
  }
}

__global__ void k_ids(const int* __restrict__ q_data, const u32* __restrict__ RANKQ,
                      float* __restrict__ out_ids){
  int i = blockIdx.x*blockDim.x + threadIdx.x;
  if (i >= NSAMP) return;
  out_ids[i] = (float)RANKQ[clampq(q_data[i])];
}

// LSTM v4: ONE wave per batch. Lane u owns unit u and computes ALL FOUR gate
// dots (4 rows of W_hh in 256 VGPRs, full h replicated in 64 VGPRs -> 256 pure
// FMAs/step, no cross-wave traffic). h-exchange is a single ds_write + 16
// uniform-address ds_read_b128 broadcasts behind a single-wave barrier (~free).
// XW4 row is read directly from global with depth-2 prefetch (no LDS staging).
// Rationale: old 4-wave version was latency-bound at ~1700 cyc/step (VALUBusy
// 35%, 1 wave/SIMD, cross-SIMD barrier + LDS RT on the critical path each step).
__global__ __launch_bounds__(64, 1) void k_lstm(
    const int* __restrict__ q_data, const float* __restrict__ XW4,
    const float* __restrict__ W_hh,
    const float* __restrict__ W_pred, const float* __restrict__ b_pred,
    const float* __restrict__ init_h, const float* __restrict__ init_c,
    float* __restrict__ out_pred){
  const int b = blockIdx.x;
  const int u = threadIdx.x;                    // unit 0..63
  __shared__ __align__(16) float Hbuf[SS][68];  // h history; stride 68: 16B-aligned rows, 2-way banks
  __shared__ int   sq[SS];
  __shared__ float swp[HH];

  for (int s = u; s < SS; s += 64) sq[s] = clampq(q_data[b*SS + s]);
  swp[u] = W_pred[u];

  // 4 W_hh rows for this unit: gate g row = g*HH + u  (i,f,g,o order)
  float wi[HH], wf[HH], wg[HH], wo[HH];
  {
    const float4* r0 = (const float4*)(W_hh + (size_t)(0*HH + u)*HH);
    const float4* r1 = (const float4*)(W_hh + (size_t)(1*HH + u)*HH);
    const float4* r2 = (const float4*)(W_hh + (size_t)(2*HH + u)*HH);
    const float4* r3 = (const float4*)(W_hh + (size_t)(3*HH + u)*HH);
    #pragma unroll
    for (int j4 = 0; j4 < HH/4; ++j4) {
      float4 a = r0[j4]; wi[4*j4]=a.x; wi[4*j4+1]=a.y; wi[4*j4+2]=a.z; wi[4*j4+3]=a.w;
      float4 e = r1[j4]; wf[4*j4]=e.x; wf[4*j4+1]=e.y; wf[4*j4+2]=e.z; wf[4*j4+3]=e.w;
      float4 f = r2[j4]; wg[4*j4]=f.x; wg[4*j4+1]=f.y; wg[4*j4+2]=f.z; wg[4*j4+3]=f.w;
      float4 g = r3[j4]; wo[4*j4]=g.x; wo[4*j4+1]=g.y; wo[4*j4+2]=g.z; wo[4*j4+3]=g.w;
    }
  }
  float hfull[HH];                              // replicated h (identical in all lanes)
  {
    const float4* ih = (const float4*)(init_h + b*HH);
    #pragma unroll
    for (int j4 = 0; j4 < HH/4; ++j4) {
      float4 v = ih[j4];
      hfull[4*j4+0]=v.x; hfull[4*j4+1]=v.y; hfull[4*j4+2]=v.z; hfull[4*j4+3]=v.w;
    }
  }
  float c  = init_c[b*HH + u];
  float bp = b_pred[0];
  __syncthreads();

  // depth-2 XW prefetch: lane u reads the float4 (i,f,g,o) for its unit
  float4 xwA = *(const float4*)(XW4 + (size_t)sq[0]*256 + 4*u);
  float4 xwB = *(const float4*)(XW4 + (size_t)sq[1]*256 + 4*u);

  for (int s = 0; s < SS; ++s) {
    int sp = (s + 2 < SS) ? s + 2 : SS - 1;
    float4 xwC = *(const float4*)(XW4 + (size_t)sq[sp]*256 + 4*u);
    float ai = 0.f, af = 0.f, ag = 0.f, ao = 0.f;
    #pragma unroll
    for (int j = 0; j < HH; ++j) {
      ai += wi[j]*hfull[j];
      af += wf[j]*hfull[j];
      ag += wg[j]*hfull[j];
      ao += wo[j]*hfull[j];
    }
    ai += xwA.x; af += xwA.y; ag += xwA.z; ao += xwA.w;
    c = fsigm(af)*c + fsigm(ai)*ftanh(ag);
    float hh = fsigm(ao)*ftanh(c);
    Hbuf[s][u] = hh;
    __syncthreads();                            // single-wave barrier: just lgkm drain
    const float4* hb = (const float4*)(&Hbuf[s][0]);  // uniform-address broadcast
    #pragma unroll
    for (int j4 = 0; j4 < HH/4; ++j4) {
      float4 v = hb[j4];
      hfull[4*j4+0]=v.x; hfull[4*j4+1]=v.y; hfull[4*j4+2]=v.z; hfull[4*j4+3]=v.w;
    }
    xwA = xwB; xwB = xwC;
  }

  // pred epilogue: lane u handles steps u, u+64, u+128, u+192(<SS)
  for (int s = u; s < SS; s += 64) {
    float acc = 0.f;
    #pragma unroll 16
    for (int kk = 0; kk < HH; ++kk) {
      int k2 = (kk + u) & 63;                   // swizzle: conflict-free banks
      acc += Hbuf[s][k2] * swp[k2];
    }
    out_pred[b*SS + s] = fsigm(acc + bp);
  }
}

extern "C" void kernel_launch(void* const* d_in, const int* in_sizes, int n_in,
                              void* d_out, int out_size, void* d_ws, size_t ws_size,
                              hipStream_t stream) {
  const int*   q_data  = (const int*)d_in[0];
  const float* emb     = (const float*)d_in[1];
  const float* keym    = (const float*)d_in[2];
  const float* val     = (const float*)d_in[3];
  const float* W_ih    = (const float*)d_in[4];
  const float* W_hh    = (const float*)d_in[5];
  const float* b_ih    = (const float*)d_in[6];
  const float* b_hh    = (const float*)d_in[7];
  const float* W_pred  = (const float*)d_in[8];
  const float* b_pred  = (const float*)d_in[9];
  const float* init_h  = (const float*)d_in[10];
  const float* init_c  = (const float*)d_in[11];

  char* ws = (char*)d_ws;
  float* XW4     = (float*)(ws + 0);          // 10,241,024 (CW overlaid low 32 floats/row)
  float* VW      = (float*)(ws + 10241024);   // 32,768
  u64*  KEYT     = (u64*) (ws + 10273792);    // 80,128
  u64*  uniq     = (u64*) (ws + 10353920);    // 80,128
  u32*  RANK     = (u32*) (ws + 10434048);    // 40,192
  u32*  g_htab   = (u32*) (ws + 10474240);    // 32,768
  u32*  g_pay    = (u32*) (ws + 10507008);    // 32,768
  u32*  counter  = (u32*) (ws + 10539776);    // 64
  u32*  present  = (u32*) (ws + 10539840);    // 40,064
  u32*  RANKQ    = (u32*) (ws + 10579904);    // 40,064
  float* WQT4    = (float*)(ws + 10619968);   // 524,288
  float* KT      = (float*)(ws + 11144256);   // 16,384
  float* WVT     = (float*)(ws + 11160640);   // 262,144
  float* CW      = XW4;                       // overlay: CW[n*256+m]

  float* out_pred = (float*)d_out;
  float* out_ids  = out_pred + NSAMP;

  hipLaunchKernelGGL(k_tr,    dim3(824), dim3(256), 0, stream,
                     W_ih, keym, WQT4, KT, WVT, present);
  hipLaunchKernelGGL(k_front, dim3(NB_ATTN + MM + 200), dim3(256), 0, stream,
                     emb, KT, val, WVT, q_data, CW, KEYT, VW, present);
  hipLaunchKernelGGL(k_dedup, dim3(1), dim3(1024), 0, stream,
                     present, KEYT, g_htab, g_pay, counter, uniq);
  hipLaunchKernelGGL(k_rank,  dim3((NROWS+255)/256), dim3(256), 0, stream, uniq, counter, RANK);
  hipLaunchKernelGGL(k_qrank, dim3((NROWS+255)/256), dim3(256), 0, stream,
                     present, KEYT, g_htab, g_pay, RANK, RANKQ);
  hipLaunchKernelGGL(k_xw,    dim3((NROWS+XR-1)/XR), dim3(256), 0, stream,
                     CW, emb, VW, WQT4, b_ih, b_hh, XW4);
  hipLaunchKernelGGL(k_ids,   dim3((NSAMP+255)/256), dim3(256), 0, stream, q_data, RANKQ, out_ids);
  hipLaunchKernelGGL(k_lstm,  dim3(BB), dim3(64), 0, stream,
                     q_data, XW4, W_hh, W_pred, b_pred, init_h, init_c, out_pred);
}

// Round 2
// 319.458 us; speedup vs baseline: 1.1374x; 1.1374x over previous
//
#include <hip/hip_runtime.h>

#define BB 256
#define SS 200
#define MM 32
#define KDIM 128
#define VDIM 256
#define QDIM 128
#define HH 64
#define NROWS 10001
#define NSAMP (BB*SS)
#define INDIM (VDIM+QDIM)
#define DHS 8192
#define DHMASK (DHS-1)
#define XR 16
#define NB_ATTN 2501

typedef unsigned long long u64;
typedef unsigned int u32;
typedef float f16v __attribute__((ext_vector_type(16)));

__device__ __forceinline__ float fexp(float x){ return __builtin_amdgcn_exp2f(x * 1.44269504f); }
__device__ __forceinline__ float fsigm(float x){ return __builtin_amdgcn_rcpf(1.f + fexp(-x)); }
__device__ __forceinline__ float ftanh(float x){ return 1.f - 2.f*__builtin_amdgcn_rcpf(1.f + fexp(2.f*x)); }
__device__ __forceinline__ int clampq(int q){ return q < 0 ? 0 : (q > NROWS-1 ? NROWS-1 : q); }

__device__ __forceinline__ u32 hash64(u64 x){
  x ^= x >> 33; x *= 0xff51afd7ed558ccdULL;
  x ^= x >> 33; x *= 0xc4ceb9fe1a85ec53ULL;
  x ^= x >> 33;
  return (u32)x;
}

__device__ __forceinline__ u64 shflx64(u64 v, int m){
  int lo = __shfl_xor((int)(u32)v, m, 64);
  int hi = __shfl_xor((int)(u32)(v >> 32), m, 64);
  return ((u64)(u32)hi << 32) | (u32)lo;
}

// transposes + present init:
// WQT4[(d4*256+j)*4+dd]=W_ih[j][VDIM+4d4+dd]; KT[d*32+m]=key_mem[m][d];
// WVT[v*256+j]=W_ih[j][v]; present[:]=0
__global__ void k_tr(const float* __restrict__ W_ih, const float* __restrict__ key_mem,
                     float* __restrict__ WQT4, float* __restrict__ KT,
                     float* __restrict__ WVT, u32* __restrict__ present){
  int idx = blockIdx.x*256 + threadIdx.x;
  if (idx < 131072) {
    int dd = idx & 3, j = (idx >> 2) & 255, d4 = idx >> 10;
    WQT4[idx] = W_ih[j*INDIM + VDIM + 4*d4 + dd];
  } else if (idx < 135168) {
    int t = idx - 131072;
    int m = t & 31, d = t >> 5; KT[t] = key_mem[m*KDIM + d];
  } else if (idx < 200704) {
    int t = idx - 135168;
    int j = t & 255, v = t >> 8; WVT[v*256 + j] = W_ih[j*INDIM + v];
  } else {
    int t = idx - 200704;
    if (t < NROWS) present[t] = 0u;
  }
}

// fused front: blocks [0,2501) attn ; [2501,2533) vw ; [2533,2733) mark
__global__ __launch_bounds__(256) void k_front(
    const float* __restrict__ emb, const float* __restrict__ KT,
    const float* __restrict__ val, const float* __restrict__ WVT,
    const int* __restrict__ q_data,
    float* __restrict__ CW, u64* __restrict__ KEYT,
    float* __restrict__ VW, u32* __restrict__ present){
  int bid = blockIdx.x;
  if (bid < NB_ATTN) {
    // ---- attn: one wave per row ----
    int w = threadIdx.x >> 6, l = threadIdx.x & 63;
    int n = bid*4 + w;
    __shared__ float se[4][QDIM];
    bool valid = (n < NROWS);
    if (valid) {
      se[w][l]      = emb[n*QDIM + l];
      se[w][l + 64] = emb[n*QDIM + l + 64];
    }
    __syncthreads();
    int m = l & 31;
    float logit = 0.f;
    if (valid && l < 32)
      for (int d = 0; d < KDIM; ++d) logit += se[w][d] * KT[d*32 + m];
    float mx = logit;
    #pragma unroll
    for (int msk = 16; msk >= 1; msk >>= 1) mx = fmaxf(mx, __shfl_xor(mx, msk, 64));
    float e = (l < 32) ? expf(logit - mx) : 0.f;    // precise expf: trit boundaries
    float sum = e;
    #pragma unroll
    for (int msk = 16; msk >= 1; msk >>= 1) sum += __shfl_xor(sum, msk, 64);
    float cw = e / sum;
    float wv = fminf((cw - 0.075f)/0.013f, (1.0f - cw)/0.912f);
    wv = fmaxf(wv, 0.f);
    int iv = (wv >= 0.6f) ? 2 : ((wv >= 0.1f) ? 1 : 0);
    int ee = (m < 16) ? m + 16 : m - 16;   // key = kh*3^16 + kl (reference packing)
    u64 p3 = 1;
    for (int i = 0; i < 31; ++i) if (i < ee) p3 *= 3ULL;
    u64 term = (valid && l < 32) ? (u64)iv * p3 : 0ULL;
    #pragma unroll
    for (int msk = 16; msk >= 1; msk >>= 1) term += shflx64(term, msk);
    if (valid && l < 32) CW[n*256 + m] = cw;
    if (valid && l == 0) KEYT[n] = term;
  } else if (bid < NB_ATTN + MM) {
    // ---- vw: VW[m][j] = sum_v val[m][v]*WVT[v][j] ----
    int m = bid - NB_ATTN, j = threadIdx.x;
    __shared__ float sval[VDIM];
    sval[j] = val[m*VDIM + j];
    __syncthreads();
    float a0=0.f, a1=0.f, a2=0.f, a3=0.f;
    for (int v = 0; v < VDIM; v += 4) {
      a0 += sval[v+0]*WVT[(v+0)*256 + j];
      a1 += sval[v+1]*WVT[(v+1)*256 + j];
      a2 += sval[v+2]*WVT[(v+2)*256 + j];
      a3 += sval[v+3]*WVT[(v+3)*256 + j];
    }
    VW[m*256 + j] = (a0+a1)+(a2+a3);
  } else {
    // ---- mark ----
    int i = (bid - NB_ATTN - MM)*256 + threadIdx.x;
    if (i < NSAMP) present[clampq(q_data[i])] = 1u;
  }
}

// XW4 row = bias + cw.VW + emb.WqT: 16 rows/block tiled GEMM
__global__ __launch_bounds__(256) void k_xw(
    const float* __restrict__ CW, const float* __restrict__ emb,
    const float* __restrict__ VW, const float* __restrict__ WQT4,
    const float* __restrict__ b_ih, const float* __restrict__ b_hh,
    float* __restrict__ XW4){
  int base = blockIdx.x * XR;
  int j = threadIdx.x;
  __shared__ float scw[XR][32];
  __shared__ __align__(16) float ses[XR][QDIM];
  for (int idx = j; idx < XR*32; idx += 256) {
    int r = idx >> 5, m = idx & 31, n = base + r;
    scw[r][m] = (n < NROWS) ? CW[n*256 + m] : 0.f;
  }
  for (int idx = j; idx < XR*QDIM; idx += 256) {
    int r = idx >> 7, d = idx & 127, n = base + r;
    ses[r][d] = (n < NROWS) ? emb[n*QDIM + d] : 0.f;
  }
  __syncthreads();
  float bias = b_ih[j] + b_hh[j];
  float acc[XR];
  #pragma unroll
  for (int r = 0; r < XR; ++r) acc[r] = bias;
  for (int m = 0; m < MM; ++m) {
    float wv = VW[m*256 + j];
    #pragma unroll
    for (int r = 0; r < XR; ++r) acc[r] += scw[r][m] * wv;
  }
  for (int d4 = 0; d4 < QDIM/4; ++d4) {
    float4 wq = *(const float4*)(WQT4 + d4*1024 + j*4);
    #pragma unroll
    for (int r = 0; r < XR; ++r) {
      float4 ev = *(const float4*)(&ses[r][4*d4]);
      acc[r] += ev.x*wq.x + ev.y*wq.y + ev.z*wq.z + ev.w*wq.w;
    }
  }
  int gate = j >> 6, unit = j & 63;
  #pragma unroll
  for (int r = 0; r < XR; ++r)
    if (base + r < NROWS) XW4[(size_t)(base + r)*256 + 4*unit + gate] = acc[r];
}

__global__ __launch_bounds__(1024) void k_dedup(
    const u32* __restrict__ present, const u64* __restrict__ KEYT,
    u32* __restrict__ g_htab, u32* __restrict__ g_pay,
    u32* __restrict__ counter, u64* __restrict__ uniq){
  __shared__ u32 sh_tab[DHS];
  __shared__ u32 sh_pay[DHS];
  __shared__ u32 sh_cnt;
  int tid = threadIdx.x;
  for (int i = tid; i < DHS; i += 1024) sh_tab[i] = 0u;
  if (tid == 0) sh_cnt = 0u;
  __syncthreads();
  for (int n = tid; n < NROWS; n += 1024) {
    if (present[n] != 1u) continue;
    u64 key = KEYT[n];
    u32 h = hash64(key) & DHMASK;
    while (true) {
      u32 cur = sh_tab[h];
      if (cur != 0u) {
        if (KEYT[cur-1u] == key) break;
        h = (h + 1) & DHMASK; continue;
      }
      u32 prev = atomicCAS(&sh_tab[h], 0u, (u32)(n + 1));
      if (prev == 0u) {
        u32 idx = atomicAdd(&sh_cnt, 1u);
        uniq[idx] = key;
        sh_pay[h] = idx;
        break;
      }
      if (KEYT[prev-1u] == key) break;
      h = (h + 1) & DHMASK;
    }
  }
  __syncthreads();
  for (int i = tid; i < DHS; i += 1024) {
    u32 v = sh_tab[i];
    g_htab[i] = v;
    g_pay[i]  = v ? sh_pay[i] : 0u;
  }
  if (tid == 0) *counter = sh_cnt;
}

__global__ __launch_bounds__(256) void k_rank(const u64* __restrict__ uniq,
                                              const u32* __restrict__ counter,
                                              u32* __restrict__ RANK){
  __shared__ u64 chunk[2048];
  u32 U = *counter;
  int u = blockIdx.x*256 + threadIdx.x;
  u64 mykey = (u < (int)U) ? uniq[u] : 0;
  u32 cnt = 0;
  for (u32 base = 0; base < U; base += 2048) {
    u32 n = (U - base < 2048u) ? (U - base) : 2048u;
    __syncthreads();
    for (u32 t = threadIdx.x; t < n; t += 256) chunk[t] = uniq[base + t];
    __syncthreads();
    if (u < (int)U)
      for (u32 j = 0; j < n; ++j) cnt += (chunk[j] < mykey) ? 1u : 0u;
  }
  if (u < (int)U) RANK[u] = cnt;
}

__global__ void k_qrank(const u32* __restrict__ present, const u64* __restrict__ KEYT,
                        const u32* __restrict__ g_htab, const u32* __restrict__ g_pay,
                        const u32* __restrict__ RANK, u32* __restrict__ RANKQ){
  int n = blockIdx.x*blockDim.x + threadIdx.x;
  if (n >= NROWS || present[n] != 1u) return;
  u64 key = KEYT[n];
  u32 h = hash64(key) & DHMASK;
  while (true) {
    u32 cur = g_htab[h];
    if (cur != 0u && KEYT[cur-1u] == key) { RANKQ[n] = RANK[g_pay[h]]; return; }
    h = (h + 1) & DHMASK;
  }
}

__global__ void k_ids(const int* __restrict__ q_data, const u32* __restrict__ RANKQ,
                      float* __restrict__ out_ids){
  int i = blockIdx.x*blockDim.x + threadIdx.x;
  if (i >= NSAMP) return;
  out_ids[i] = (float)RANKQ[clampq(q_data[i])];
}

// 16 independent FMA chains per gate-group via separate partial accumulators
#define DOT16(acc, W, H) do { \
  acc += (W)[0]*(H)[0];   acc += (W)[1]*(H)[1];   acc += (W)[2]*(H)[2];   acc += (W)[3]*(H)[3]; \
  acc += (W)[4]*(H)[4];   acc += (W)[5]*(H)[5];   acc += (W)[6]*(H)[6];   acc += (W)[7]*(H)[7]; \
  acc += (W)[8]*(H)[8];   acc += (W)[9]*(H)[9];   acc += (W)[10]*(H)[10]; acc += (W)[11]*(H)[11]; \
  acc += (W)[12]*(H)[12]; acc += (W)[13]*(H)[13]; acc += (W)[14]*(H)[14]; acc += (W)[15]*(H)[15]; \
} while(0)

// LSTM v5: ONE wave per batch, W_hh in NAMED ext_vector_type(16) SSA values.
// v4 post-mortem: VGPR_Count=180 proved the float[64] arrays were never
// promoted (PromoteAlloca bails on ~1KB allocas) -> per-step scratch/L2
// reloads = ~2250 stall cyc/step. Named 16-wide vectors with constant-index
// access are first-class SSA: no alloca exists, RA must keep them resident
// (budget 512 via __launch_bounds__(64,1); need ~360).
__global__ __launch_bounds__(64, 1) void k_lstm(
    const int* __restrict__ q_data, const float* __restrict__ XW4,
    const float* __restrict__ W_hh,
    const float* __restrict__ W_pred, const float* __restrict__ b_pred,
    const float* __restrict__ init_h, const float* __restrict__ init_c,
    float* __restrict__ out_pred){
  const int b = blockIdx.x;
  const int u = threadIdx.x;                    // unit 0..63
  __shared__ __align__(64) float Hbuf[SS][64];  // 256B rows: f16v-aligned broadcast reads
  __shared__ int   sq[SS];
  __shared__ float swp[HH];

  for (int s = u; s < SS; s += 64) sq[s] = clampq(q_data[b*SS + s]);
  swp[u] = W_pred[u];

  // 4 W_hh rows for this unit (gate g row = g*HH + u; i,f,g,o order).
  // Rows are 256B apart from a 256B-aligned base -> 64B f16v loads are aligned.
  const f16v* r0 = (const f16v*)(W_hh + (size_t)(0*HH + u)*HH);
  const f16v* r1 = (const f16v*)(W_hh + (size_t)(1*HH + u)*HH);
  const f16v* r2 = (const f16v*)(W_hh + (size_t)(2*HH + u)*HH);
  const f16v* r3 = (const f16v*)(W_hh + (size_t)(3*HH + u)*HH);
  f16v Wi0=r0[0], Wi1=r0[1], Wi2=r0[2], Wi3=r0[3];
  f16v Wf0=r1[0], Wf1=r1[1], Wf2=r1[2], Wf3=r1[3];
  f16v Wg0=r2[0], Wg1=r2[1], Wg2=r2[2], Wg3=r2[3];
  f16v Wo0=r3[0], Wo1=r3[1], Wo2=r3[2], Wo3=r3[3];

  // replicated h (identical in all lanes); init_h row b is 256B-aligned
  f16v H0, H1, H2, H3;
  {
    const f16v* ihv = (const f16v*)(init_h + (size_t)b*HH);
    H0 = ihv[0]; H1 = ihv[1]; H2 = ihv[2]; H3 = ihv[3];
  }
  float c  = init_c[b*HH + u];
  float bp = b_pred[0];
  __syncthreads();

  // depth-2 XW prefetch: lane u reads the float4 (i,f,g,o) for its unit
  float4 xwA = *(const float4*)(XW4 + (size_t)sq[0]*256 + 4*u);
  float4 xwB = *(const float4*)(XW4 + (size_t)sq[1]*256 + 4*u);

  for (int s = 0; s < SS; ++s) {
    int sp = (s + 2 < SS) ? s + 2 : SS - 1;
    float4 xwC = *(const float4*)(XW4 + (size_t)sq[sp]*256 + 4*u);
    float i0=0.f,i1=0.f,i2=0.f,i3=0.f, f0=0.f,f1=0.f,f2=0.f,f3=0.f;
    float g0=0.f,g1=0.f,g2=0.f,g3=0.f, o0=0.f,o1=0.f,o2=0.f,o3=0.f;
    DOT16(i0, Wi0, H0); DOT16(i1, Wi1, H1); DOT16(i2, Wi2, H2); DOT16(i3, Wi3, H3);
    DOT16(f0, Wf0, H0); DOT16(f1, Wf1, H1); DOT16(f2, Wf2, H2); DOT16(f3, Wf3, H3);
    DOT16(g0, Wg0, H0); DOT16(g1, Wg1, H1); DOT16(g2, Wg2, H2); DOT16(g3, Wg3, H3);
    DOT16(o0, Wo0, H0); DOT16(o1, Wo1, H1); DOT16(o2, Wo2, H2); DOT16(o3, Wo3, H3);
    float ai = xwA.x + ((i0+i1)+(i2+i3));
    float af = xwA.y + ((f0+f1)+(f2+f3));
    float ag = xwA.z + ((g0+g1)+(g2+g3));
    float ao = xwA.w + ((o0+o1)+(o2+o3));
    c = fsigm(af)*c + fsigm(ai)*ftanh(ag);
    float hh = fsigm(ao)*ftanh(c);
    Hbuf[s][u] = hh;
    __syncthreads();                            // single-wave barrier: just lgkm drain
    const f16v* hb = (const f16v*)(&Hbuf[s][0]);  // uniform-address broadcast
    H0 = hb[0]; H1 = hb[1]; H2 = hb[2]; H3 = hb[3];
    xwA = xwB; xwB = xwC;
  }
  __syncthreads();

  // pred epilogue: lane u handles steps u, u+64, u+128, u+192(<SS)
  for (int s = u; s < SS; s += 64) {
    float acc = 0.f;
    #pragma unroll 16
    for (int kk = 0; kk < HH; ++kk) {
      int k2 = (kk + u) & 63;                   // swizzle: <=2-way banks (free)
      acc += Hbuf[s][k2] * swp[k2];
    }
    out_pred[b*SS + s] = fsigm(acc + bp);
  }
}

extern "C" void kernel_launch(void* const* d_in, const int* in_sizes, int n_in,
                              void* d_out, int out_size, void* d_ws, size_t ws_size,
                              hipStream_t stream) {
  const int*   q_data  = (const int*)d_in[0];
  const float* emb     = (const float*)d_in[1];
  const float* keym    = (const float*)d_in[2];
  const float* val     = (const float*)d_in[3];
  const float* W_ih    = (const float*)d_in[4];
  const float* W_hh    = (const float*)d_in[5];
  const float* b_ih    = (const float*)d_in[6];
  const float* b_hh    = (const float*)d_in[7];
  const float* W_pred  = (const float*)d_in[8];
  const float* b_pred  = (const float*)d_in[9];
  const float* init_h  = (const float*)d_in[10];
  const float* init_c  = (const float*)d_in[11];

  char* ws = (char*)d_ws;
  float* XW4     = (float*)(ws + 0);          // 10,241,024 (CW overlaid low 32 floats/row)
  float* VW      = (float*)(ws + 10241024);   // 32,768
  u64*  KEYT     = (u64*) (ws + 10273792);    // 80,128
  u64*  uniq     = (u64*) (ws + 10353920);    // 80,128
  u32*  RANK     = (u32*) (ws + 10434048);    // 40,192
  u32*  g_htab   = (u32*) (ws + 10474240);    // 32,768
  u32*  g_pay    = (u32*) (ws + 10507008);    // 32,768
  u32*  counter  = (u32*) (ws + 10539776);    // 64
  u32*  present  = (u32*) (ws + 10539840);    // 40,064
  u32*  RANKQ    = (u32*) (ws + 10579904);    // 40,064
  float* WQT4    = (float*)(ws + 10619968);   // 524,288
  float* KT      = (float*)(ws + 11144256);   // 16,384
  float* WVT     = (float*)(ws + 11160640);   // 262,144
  float* CW      = XW4;                       // overlay: CW[n*256+m]

  float* out_pred = (float*)d_out;
  float* out_ids  = out_pred + NSAMP;

  hipLaunchKernelGGL(k_tr,    dim3(824), dim3(256), 0, stream,
                     W_ih, keym, WQT4, KT, WVT, present);
  hipLaunchKernelGGL(k_front, dim3(NB_ATTN + MM + 200), dim3(256), 0, stream,
                     emb, KT, val, WVT, q_data, CW, KEYT, VW, present);
  hipLaunchKernelGGL(k_dedup, dim3(1), dim3(1024), 0, stream,
                     present, KEYT, g_htab, g_pay, counter, uniq);
  hipLaunchKernelGGL(k_rank,  dim3((NROWS+255)/256), dim3(256), 0, stream, uniq, counter, RANK);
  hipLaunchKernelGGL(k_qrank, dim3((NROWS+255)/256), dim3(256), 0, stream,
                     present, KEYT, g_htab, g_pay, RANK, RANKQ);
  hipLaunchKernelGGL(k_xw,    dim3((NROWS+XR-1)/XR), dim3(256), 0, stream,
                     CW, emb, VW, WQT4, b_ih, b_hh, XW4);
  hipLaunchKernelGGL(k_ids,   dim3((NSAMP+255)/256), dim3(256), 0, stream, q_data, RANKQ, out_ids);
  hipLaunchKernelGGL(k_lstm,  dim3(BB), dim3(64), 0, stream,
                     q_data, XW4, W_hh, W_pred, b_pred, init_h, init_c, out_pred);
}

// Round 3
// 244.544 us; speedup vs baseline: 1.4859x; 1.3063x over previous
//
#include <hip/hip_runtime.h>

#define BB 256
#define SS 200
#define MM 32
#define KDIM 128
#define VDIM 256
#define QDIM 128
#define HH 64
#define NROWS 10001
#define NSAMP (BB*SS)
#define INDIM (VDIM+QDIM)
#define DHS 8192
#define DHMASK (DHS-1)
#define XR 16
#define NB_ATTN 2501

typedef unsigned long long u64;
typedef unsigned int u32;
typedef float f16v __attribute__((ext_vector_type(16)));

__device__ __forceinline__ float fexp(float x){ return __builtin_amdgcn_exp2f(x * 1.44269504f); }
__device__ __forceinline__ float fsigm(float x){ return __builtin_amdgcn_rcpf(1.f + fexp(-x)); }
__device__ __forceinline__ float ftanh(float x){ return 1.f - 2.f*__builtin_amdgcn_rcpf(1.f + fexp(2.f*x)); }
__device__ __forceinline__ int clampq(int q){ return q < 0 ? 0 : (q > NROWS-1 ? NROWS-1 : q); }

__device__ __forceinline__ u32 hash64(u64 x){
  x ^= x >> 33; x *= 0xff51afd7ed558ccdULL;
  x ^= x >> 33; x *= 0xc4ceb9fe1a85ec53ULL;
  x ^= x >> 33;
  return (u32)x;
}

__device__ __forceinline__ u64 shflx64(u64 v, int m){
  int lo = __shfl_xor((int)(u32)v, m, 64);
  int hi = __shfl_xor((int)(u32)(v >> 32), m, 64);
  return ((u64)(u32)hi << 32) | (u32)lo;
}

// transposes + present init:
// WQT4[(d4*256+j)*4+dd]=W_ih[j][VDIM+4d4+dd]; KT[d*32+m]=key_mem[m][d];
// WVT[v*256+j]=W_ih[j][v]; present[:]=0
__global__ void k_tr(const float* __restrict__ W_ih, const float* __restrict__ key_mem,
                     float* __restrict__ WQT4, float* __restrict__ KT,
                     float* __restrict__ WVT, u32* __restrict__ present){
  int idx = blockIdx.x*256 + threadIdx.x;
  if (idx < 131072) {
    int dd = idx & 3, j = (idx >> 2) & 255, d4 = idx >> 10;
    WQT4[idx] = W_ih[j*INDIM + VDIM + 4*d4 + dd];
  } else if (idx < 135168) {
    int t = idx - 131072;
    int m = t & 31, d = t >> 5; KT[t] = key_mem[m*KDIM + d];
  } else if (idx < 200704) {
    int t = idx - 135168;
    int j = t & 255, v = t >> 8; WVT[v*256 + j] = W_ih[j*INDIM + v];
  } else {
    int t = idx - 200704;
    if (t < NROWS) present[t] = 0u;
  }
}

// fused front: blocks [0,2501) attn ; [2501,2533) vw ; [2533,2733) mark
__global__ __launch_bounds__(256) void k_front(
    const float* __restrict__ emb, const float* __restrict__ KT,
    const float* __restrict__ val, const float* __restrict__ WVT,
    const int* __restrict__ q_data,
    float* __restrict__ CW, u64* __restrict__ KEYT,
    float* __restrict__ VW, u32* __restrict__ present){
  int bid = blockIdx.x;
  if (bid < NB_ATTN) {
    // ---- attn: one wave per row ----
    int w = threadIdx.x >> 6, l = threadIdx.x & 63;
    int n = bid*4 + w;
    __shared__ float se[4][QDIM];
    bool valid = (n < NROWS);
    if (valid) {
      se[w][l]      = emb[n*QDIM + l];
      se[w][l + 64] = emb[n*QDIM + l + 64];
    }
    __syncthreads();
    int m = l & 31;
    float logit = 0.f;
    if (valid && l < 32)
      for (int d = 0; d < KDIM; ++d) logit += se[w][d] * KT[d*32 + m];
    float mx = logit;
    #pragma unroll
    for (int msk = 16; msk >= 1; msk >>= 1) mx = fmaxf(mx, __shfl_xor(mx, msk, 64));
    float e = (l < 32) ? expf(logit - mx) : 0.f;    // precise expf: trit boundaries
    float sum = e;
    #pragma unroll
    for (int msk = 16; msk >= 1; msk >>= 1) sum += __shfl_xor(sum, msk, 64);
    float cw = e / sum;
    float wv = fminf((cw - 0.075f)/0.013f, (1.0f - cw)/0.912f);
    wv = fmaxf(wv, 0.f);
    int iv = (wv >= 0.6f) ? 2 : ((wv >= 0.1f) ? 1 : 0);
    int ee = (m < 16) ? m + 16 : m - 16;   // key = kh*3^16 + kl (reference packing)
    u64 p3 = 1;
    for (int i = 0; i < 31; ++i) if (i < ee) p3 *= 3ULL;
    u64 term = (valid && l < 32) ? (u64)iv * p3 : 0ULL;
    #pragma unroll
    for (int msk = 16; msk >= 1; msk >>= 1) term += shflx64(term, msk);
    if (valid && l < 32) CW[n*256 + m] = cw;
    if (valid && l == 0) KEYT[n] = term;
  } else if (bid < NB_ATTN + MM) {
    // ---- vw: VW[m][j] = sum_v val[m][v]*WVT[v][j] ----
    int m = bid - NB_ATTN, j = threadIdx.x;
    __shared__ float sval[VDIM];
    sval[j] = val[m*VDIM + j];
    __syncthreads();
    float a0=0.f, a1=0.f, a2=0.f, a3=0.f;
    for (int v = 0; v < VDIM; v += 4) {
      a0 += sval[v+0]*WVT[(v+0)*256 + j];
      a1 += sval[v+1]*WVT[(v+1)*256 + j];
      a2 += sval[v+2]*WVT[(v+2)*256 + j];
      a3 += sval[v+3]*WVT[(v+3)*256 + j];
    }
    VW[m*256 + j] = (a0+a1)+(a2+a3);
  } else {
    // ---- mark ----
    int i = (bid - NB_ATTN - MM)*256 + threadIdx.x;
    if (i < NSAMP) present[clampq(q_data[i])] = 1u;
  }
}

// XW4 row = bias + cw.VW + emb.WqT: 16 rows/block tiled GEMM
__global__ __launch_bounds__(256) void k_xw(
    const float* __restrict__ CW, const float* __restrict__ emb,
    const float* __restrict__ VW, const float* __restrict__ WQT4,
    const float* __restrict__ b_ih, const float* __restrict__ b_hh,
    float* __restrict__ XW4){
  int base = blockIdx.x * XR;
  int j = threadIdx.x;
  __shared__ float scw[XR][32];
  __shared__ __align__(16) float ses[XR][QDIM];
  for (int idx = j; idx < XR*32; idx += 256) {
    int r = idx >> 5, m = idx & 31, n = base + r;
    scw[r][m] = (n < NROWS) ? CW[n*256 + m] : 0.f;
  }
  for (int idx = j; idx < XR*QDIM; idx += 256) {
    int r = idx >> 7, d = idx & 127, n = base + r;
    ses[r][d] = (n < NROWS) ? emb[n*QDIM + d] : 0.f;
  }
  __syncthreads();
  float bias = b_ih[j] + b_hh[j];
  float acc[XR];
  #pragma unroll
  for (int r = 0; r < XR; ++r) acc[r] = bias;
  for (int m = 0; m < MM; ++m) {
    float wv = VW[m*256 + j];
    #pragma unroll
    for (int r = 0; r < XR; ++r) acc[r] += scw[r][m] * wv;
  }
  for (int d4 = 0; d4 < QDIM/4; ++d4) {
    float4 wq = *(const float4*)(WQT4 + d4*1024 + j*4);
    #pragma unroll
    for (int r = 0; r < XR; ++r) {
      float4 ev = *(const float4*)(&ses[r][4*d4]);
      acc[r] += ev.x*wq.x + ev.y*wq.y + ev.z*wq.z + ev.w*wq.w;
    }
  }
  int gate = j >> 6, unit = j & 63;
  #pragma unroll
  for (int r = 0; r < XR; ++r)
    if (base + r < NROWS) XW4[(size_t)(base + r)*256 + 4*unit + gate] = acc[r];
}

__global__ __launch_bounds__(1024) void k_dedup(
    const u32* __restrict__ present, const u64* __restrict__ KEYT,
    u32* __restrict__ g_htab, u32* __restrict__ g_pay,
    u32* __restrict__ counter, u64* __restrict__ uniq){
  __shared__ u32 sh_tab[DHS];
  __shared__ u32 sh_pay[DHS];
  __shared__ u32 sh_cnt;
  int tid = threadIdx.x;
  for (int i = tid; i < DHS; i += 1024) sh_tab[i] = 0u;
  if (tid == 0) sh_cnt = 0u;
  __syncthreads();
  for (int n = tid; n < NROWS; n += 1024) {
    if (present[n] != 1u) continue;
    u64 key = KEYT[n];
    u32 h = hash64(key) & DHMASK;
    while (true) {
      u32 cur = sh_tab[h];
      if (cur != 0u) {
        if (KEYT[cur-1u] == key) break;
        h = (h + 1) & DHMASK; continue;
      }
      u32 prev = atomicCAS(&sh_tab[h], 0u, (u32)(n + 1));
      if (prev == 0u) {
        u32 idx = atomicAdd(&sh_cnt, 1u);
        uniq[idx] = key;
        sh_pay[h] = idx;
        break;
      }
      if (KEYT[prev-1u] == key) break;
      h = (h + 1) & DHMASK;
    }
  }
  __syncthreads();
  for (int i = tid; i < DHS; i += 1024) {
    u32 v = sh_tab[i];
    g_htab[i] = v;
    g_pay[i]  = v ? sh_pay[i] : 0u;
  }
  if (tid == 0) *counter = sh_cnt;
}

__global__ __launch_bounds__(256) void k_rank(const u64* __restrict__ uniq,
                                              const u32* __restrict__ counter,
                                              u32* __restrict__ RANK){
  __shared__ u64 chunk[2048];
  u32 U = *counter;
  int u = blockIdx.x*256 + threadIdx.x;
  u64 mykey = (u < (int)U) ? uniq[u] : 0;
  u32 cnt = 0;
  for (u32 base = 0; base < U; base += 2048) {
    u32 n = (U - base < 2048u) ? (U - base) : 2048u;
    __syncthreads();
    for (u32 t = threadIdx.x; t < n; t += 256) chunk[t] = uniq[base + t];
    __syncthreads();
    if (u < (int)U)
      for (u32 j = 0; j < n; ++j) cnt += (chunk[j] < mykey) ? 1u : 0u;
  }
  if (u < (int)U) RANK[u] = cnt;
}

__global__ void k_qrank(const u32* __restrict__ present, const u64* __restrict__ KEYT,
                        const u32* __restrict__ g_htab, const u32* __restrict__ g_pay,
                        const u32* __restrict__ RANK, u32* __restrict__ RANKQ){
  int n = blockIdx.x*blockDim.x + threadIdx.x;
  if (n >= NROWS || present[n] != 1u) return;
  u64 key = KEYT[n];
  u32 h = hash64(key) & DHMASK;
  while (true) {
    u32 cur = g_htab[h];
    if (cur != 0u && KEYT[cur-1u] == key) { RANKQ[n] = RANK[g_pay[h]]; return; }
    h = (h + 1) & DHMASK;
  }
}

__global__ void k_ids(const int* __restrict__ q_data, const u32* __restrict__ RANKQ,
                      float* __restrict__ out_ids){
  int i = blockIdx.x*blockDim.x + threadIdx.x;
  if (i >= NSAMP) return;
  out_ids[i] = (float)RANKQ[clampq(q_data[i])];
}

// 16 independent FMA chains via separate partial accumulators
#define DOT16(acc, W, H) do { \
  acc += (W)[0]*(H)[0];   acc += (W)[1]*(H)[1];   acc += (W)[2]*(H)[2];   acc += (W)[3]*(H)[3]; \
  acc += (W)[4]*(H)[4];   acc += (W)[5]*(H)[5];   acc += (W)[6]*(H)[6];   acc += (W)[7]*(H)[7]; \
  acc += (W)[8]*(H)[8];   acc += (W)[9]*(H)[9];   acc += (W)[10]*(H)[10]; acc += (W)[11]*(H)[11]; \
  acc += (W)[12]*(H)[12]; acc += (W)[13]*(H)[13]; acc += (W)[14]*(H)[14]; acc += (W)[15]*(H)[15]; \
} while(0)

// LSTM v6: 2 waves per batch, K-split. v4/v5 post-mortem: non-MFMA code caps at
// 256 ARCH VGPRs (512 file is VGPR+AGPR unified; v_fma can't read AGPR), and the
// 1-wave design needed ~360 live floats -> RA rematerialized W loads in-loop
// (64KB/step from L2 @ ~56B/cy/CU ~= the whole 2130 cyc/step). Here wave w holds
// per lane u: 4 gate rows x its h-HALF (128 VGPR) + half-h replicated (32) ->
// ~200 live, fits. Per step: 128 FMAs/wave (SIMDs parallel), float4 partial
// exchange via parity-double-buffered LDS + ONE barrier, redundant c/h update in
// both waves; h write->broadcast-read is INTRA-wave only (wave w's lanes
// [32w,32w+32) produce exactly the half wave w consumes) -> no second barrier.
// Sum association ((p0+p1)+oth) == v5's ((i0+i1)+(i2+i3)): bit-identical.
__global__ __launch_bounds__(128, 1) void k_lstm(
    const int* __restrict__ q_data, const float* __restrict__ XW4,
    const float* __restrict__ W_hh,
    const float* __restrict__ W_pred, const float* __restrict__ b_pred,
    const float* __restrict__ init_h, const float* __restrict__ init_c,
    float* __restrict__ out_pred){
  const int b = blockIdx.x;
  const int t = threadIdx.x;
  const int w = t >> 6, u = t & 63;             // wave 0..1, unit 0..63
  __shared__ __align__(64) float Hbuf[SS][64];  // h history; 256B rows
  __shared__ __align__(16) float4 PART[2][2][64]; // [step parity][wave][unit]
  __shared__ int   sq[SS];
  __shared__ float swp[HH];

  for (int s = t; s < SS; s += 128) sq[s] = clampq(q_data[b*SS + s]);
  if (t < HH) swp[t] = W_pred[t];

  // W_hh rows for unit u, all 4 gates, restricted to this wave's h-half.
  // Row (g*HH+u) stride 256B; half offset 128B*w -> 64B-aligned f16v loads.
  const float* wb = W_hh + (size_t)u*HH + 32*w;
  f16v Wi0 = *(const f16v*)(wb +     0), Wi1 = *(const f16v*)(wb +     0 + 16);
  f16v Wf0 = *(const f16v*)(wb +  4096), Wf1 = *(const f16v*)(wb +  4096 + 16);
  f16v Wg0 = *(const f16v*)(wb +  8192), Wg1 = *(const f16v*)(wb +  8192 + 16);
  f16v Wo0 = *(const f16v*)(wb + 12288), Wo1 = *(const f16v*)(wb + 12288 + 16);

  // replicated h-half (identical in all lanes of this wave)
  f16v H0, H1;
  {
    const f16v* ihv = (const f16v*)(init_h + (size_t)b*HH + 32*w);
    H0 = ihv[0]; H1 = ihv[1];
  }
  float c  = init_c[b*HH + u];                  // both waves track c[u] redundantly
  float bp = b_pred[0];
  __syncthreads();

  // depth-2 XW prefetch (both waves load the same float4: L1-hit, harmless)
  float4 xwA = *(const float4*)(XW4 + (size_t)sq[0]*256 + 4*u);
  float4 xwB = *(const float4*)(XW4 + (size_t)sq[1]*256 + 4*u);

  for (int s = 0; s < SS; ++s) {
    int sp = (s + 2 < SS) ? s + 2 : SS - 1;
    float4 xwC = *(const float4*)(XW4 + (size_t)sq[sp]*256 + 4*u);
    float pi0=0.f,pi1=0.f, pf0=0.f,pf1=0.f, pg0=0.f,pg1=0.f, po0=0.f,po1=0.f;
    DOT16(pi0, Wi0, H0); DOT16(pi1, Wi1, H1);
    DOT16(pf0, Wf0, H0); DOT16(pf1, Wf1, H1);
    DOT16(pg0, Wg0, H0); DOT16(pg1, Wg1, H1);
    DOT16(po0, Wo0, H0); DOT16(po1, Wo1, H1);
    int pr = s & 1;
    PART[pr][w][u] = make_float4(pi0+pi1, pf0+pf1, pg0+pg1, po0+po1);
    __syncthreads();                            // the one cross-wave sync per step
    float4 oth = PART[pr][w^1][u];
    float ai = xwA.x + ((pi0+pi1) + oth.x);
    float af = xwA.y + ((pf0+pf1) + oth.y);
    float ag = xwA.z + ((pg0+pg1) + oth.z);
    float ao = xwA.w + ((po0+po1) + oth.w);
    c = fsigm(af)*c + fsigm(ai)*ftanh(ag);
    float hh = fsigm(ao)*ftanh(c);
    if ((u >> 5) == w) Hbuf[s][u] = hh;         // my lanes produce exactly my half
    const f16v* hb = (const f16v*)(&Hbuf[s][32*w]); // intra-wave: lgkm-ordered
    H0 = hb[0]; H1 = hb[1];
    xwA = xwB; xwB = xwC;
  }
  __syncthreads();

  // pred epilogue over full Hbuf (both halves)
  for (int s = t; s < SS; s += 128) {
    float acc = 0.f;
    #pragma unroll 16
    for (int kk = 0; kk < HH; ++kk) {
      int k2 = (kk + t) & 63;                   // swizzle: <=2-way banks (free)
      acc += Hbuf[s][k2] * swp[k2];
    }
    out_pred[b*SS + s] = fsigm(acc + bp);
  }
}

extern "C" void kernel_launch(void* const* d_in, const int* in_sizes, int n_in,
                              void* d_out, int out_size, void* d_ws, size_t ws_size,
                              hipStream_t stream) {
  const int*   q_data  = (const int*)d_in[0];
  const float* emb     = (const float*)d_in[1];
  const float* keym    = (const float*)d_in[2];
  const float* val     = (const float*)d_in[3];
  const float* W_ih    = (const float*)d_in[4];
  const float* W_hh    = (const float*)d_in[5];
  const float* b_ih    = (const float*)d_in[6];
  const float* b_hh    = (const float*)d_in[7];
  const float* W_pred  = (const float*)d_in[8];
  const float* b_pred  = (const float*)d_in[9];
  const float* init_h  = (const float*)d_in[10];
  const float* init_c  = (const float*)d_in[11];

  char* ws = (char*)d_ws;
  float* XW4     = (float*)(ws + 0);          // 10,241,024 (CW overlaid low 32 floats/row)
  float* VW      = (float*)(ws + 10241024);   // 32,768
  u64*  KEYT     = (u64*) (ws + 10273792);    // 80,128
  u64*  uniq     = (u64*) (ws + 10353920);    // 80,128
  u32*  RANK     = (u32*) (ws + 10434048);    // 40,192
  u32*  g_htab   = (u32*) (ws + 10474240);    // 32,768
  u32*  g_pay    = (u32*) (ws + 10507008);    // 32,768
  u32*  counter  = (u32*) (ws + 10539776);    // 64
  u32*  present  = (u32*) (ws + 10539840);    // 40,064
  u32*  RANKQ    = (u32*) (ws + 10579904);    // 40,064
  float* WQT4    = (float*)(ws + 10619968);   // 524,288
  float* KT      = (float*)(ws + 11144256);   // 16,384
  float* WVT     = (float*)(ws + 11160640);   // 262,144
  float* CW      = XW4;                       // overlay: CW[n*256+m]

  float* out_pred = (float*)d_out;
  float* out_ids  = out_pred + NSAMP;

  hipLaunchKernelGGL(k_tr,    dim3(824), dim3(256), 0, stream,
                     W_ih, keym, WQT4, KT, WVT, present);
  hipLaunchKernelGGL(k_front, dim3(NB_ATTN + MM + 200), dim3(256), 0, stream,
                     emb, KT, val, WVT, q_data, CW, KEYT, VW, present);
  hipLaunchKernelGGL(k_dedup, dim3(1), dim3(1024), 0, stream,
                     present, KEYT, g_htab, g_pay, counter, uniq);
  hipLaunchKernelGGL(k_rank,  dim3((NROWS+255)/256), dim3(256), 0, stream, uniq, counter, RANK);
  hipLaunchKernelGGL(k_qrank, dim3((NROWS+255)/256), dim3(256), 0, stream,
                     present, KEYT, g_htab, g_pay, RANK, RANKQ);
  hipLaunchKernelGGL(k_xw,    dim3((NROWS+XR-1)/XR), dim3(256), 0, stream,
                     CW, emb, VW, WQT4, b_ih, b_hh, XW4);
  hipLaunchKernelGGL(k_ids,   dim3((NSAMP+255)/256), dim3(256), 0, stream, q_data, RANKQ, out_ids);
  hipLaunchKernelGGL(k_lstm,  dim3(BB), dim3(128), 0, stream,
                     q_data, XW4, W_hh, W_pred, b_pred, init_h, init_c, out_pred);
}

// Round 4
// 239.745 us; speedup vs baseline: 1.5156x; 1.0200x over previous
//
#include <hip/hip_runtime.h>

#define BB 256
#define SS 200
#define MM 32
#define KDIM 128
#define VDIM 256
#define QDIM 128
#define HH 64
#define NROWS 10001
#define NSAMP (BB*SS)
#define INDIM (VDIM+QDIM)
#define DHS 8192
#define DHMASK (DHS-1)
#define XR 16
#define NB_ATTN 2501

typedef unsigned long long u64;
typedef unsigned int u32;
typedef float f16v __attribute__((ext_vector_type(16)));

__device__ __forceinline__ float fexp(float x){ return __builtin_amdgcn_exp2f(x * 1.44269504f); }
__device__ __forceinline__ float fsigm(float x){ return __builtin_amdgcn_rcpf(1.f + fexp(-x)); }
__device__ __forceinline__ float ftanh(float x){ return 1.f - 2.f*__builtin_amdgcn_rcpf(1.f + fexp(2.f*x)); }
__device__ __forceinline__ int clampq(int q){ return q < 0 ? 0 : (q > NROWS-1 ? NROWS-1 : q); }

__device__ __forceinline__ u32 hash64(u64 x){
  x ^= x >> 33; x *= 0xff51afd7ed558ccdULL;
  x ^= x >> 33; x *= 0xc4ceb9fe1a85ec53ULL;
  x ^= x >> 33;
  return (u32)x;
}

__device__ __forceinline__ u64 shflx64(u64 v, int m){
  int lo = __shfl_xor((int)(u32)v, m, 64);
  int hi = __shfl_xor((int)(u32)(v >> 32), m, 64);
  return ((u64)(u32)hi << 32) | (u32)lo;
}

// transposes + present init:
// WQT4[(d4*256+j)*4+dd]=W_ih[j][VDIM+4d4+dd]; KT[d*32+m]=key_mem[m][d];
// WVT[v*256+j]=W_ih[j][v]; present[:]=0
__global__ void k_tr(const float* __restrict__ W_ih, const float* __restrict__ key_mem,
                     float* __restrict__ WQT4, float* __restrict__ KT,
                     float* __restrict__ WVT, u32* __restrict__ present){
  int idx = blockIdx.x*256 + threadIdx.x;
  if (idx < 131072) {
    int dd = idx & 3, j = (idx >> 2) & 255, d4 = idx >> 10;
    WQT4[idx] = W_ih[j*INDIM + VDIM + 4*d4 + dd];
  } else if (idx < 135168) {
    int t = idx - 131072;
    int m = t & 31, d = t >> 5; KT[t] = key_mem[m*KDIM + d];
  } else if (idx < 200704) {
    int t = idx - 135168;
    int j = t & 255, v = t >> 8; WVT[v*256 + j] = W_ih[j*INDIM + v];
  } else {
    int t = idx - 200704;
    if (t < NROWS) present[t] = 0u;
  }
}

// fused front: blocks [0,2501) attn ; [2501,2533) vw ; [2533,2733) mark
__global__ __launch_bounds__(256) void k_front(
    const float* __restrict__ emb, const float* __restrict__ KT,
    const float* __restrict__ val, const float* __restrict__ WVT,
    const int* __restrict__ q_data,
    float* __restrict__ CW, u64* __restrict__ KEYT,
    float* __restrict__ VW, u32* __restrict__ present){
  int bid = blockIdx.x;
  if (bid < NB_ATTN) {
    // ---- attn: one wave per row ----
    int w = threadIdx.x >> 6, l = threadIdx.x & 63;
    int n = bid*4 + w;
    __shared__ float se[4][QDIM];
    bool valid = (n < NROWS);
    if (valid) {
      se[w][l]      = emb[n*QDIM + l];
      se[w][l + 64] = emb[n*QDIM + l + 64];
    }
    __syncthreads();
    int m = l & 31;
    float logit = 0.f;
    if (valid && l < 32)
      for (int d = 0; d < KDIM; ++d) logit += se[w][d] * KT[d*32 + m];
    float mx = logit;
    #pragma unroll
    for (int msk = 16; msk >= 1; msk >>= 1) mx = fmaxf(mx, __shfl_xor(mx, msk, 64));
    float e = (l < 32) ? expf(logit - mx) : 0.f;    // precise expf: trit boundaries
    float sum = e;
    #pragma unroll
    for (int msk = 16; msk >= 1; msk >>= 1) sum += __shfl_xor(sum, msk, 64);
    float cw = e / sum;
    float wv = fminf((cw - 0.075f)/0.013f, (1.0f - cw)/0.912f);
    wv = fmaxf(wv, 0.f);
    int iv = (wv >= 0.6f) ? 2 : ((wv >= 0.1f) ? 1 : 0);
    int ee = (m < 16) ? m + 16 : m - 16;   // key = kh*3^16 + kl (reference packing)
    u64 p3 = 1;
    for (int i = 0; i < 31; ++i) if (i < ee) p3 *= 3ULL;
    u64 term = (valid && l < 32) ? (u64)iv * p3 : 0ULL;
    #pragma unroll
    for (int msk = 16; msk >= 1; msk >>= 1) term += shflx64(term, msk);
    if (valid && l < 32) CW[n*256 + m] = cw;
    if (valid && l == 0) KEYT[n] = term;
  } else if (bid < NB_ATTN + MM) {
    // ---- vw: VW[m][j] = sum_v val[m][v]*WVT[v][j] ----
    int m = bid - NB_ATTN, j = threadIdx.x;
    __shared__ float sval[VDIM];
    sval[j] = val[m*VDIM + j];
    __syncthreads();
    float a0=0.f, a1=0.f, a2=0.f, a3=0.f;
    for (int v = 0; v < VDIM; v += 4) {
      a0 += sval[v+0]*WVT[(v+0)*256 + j];
      a1 += sval[v+1]*WVT[(v+1)*256 + j];
      a2 += sval[v+2]*WVT[(v+2)*256 + j];
      a3 += sval[v+3]*WVT[(v+3)*256 + j];
    }
    VW[m*256 + j] = (a0+a1)+(a2+a3);
  } else {
    // ---- mark ----
    int i = (bid - NB_ATTN - MM)*256 + threadIdx.x;
    if (i < NSAMP) present[clampq(q_data[i])] = 1u;
  }
}

// XW4 row = bias + cw.VW + emb.WqT: 16 rows/block tiled GEMM
__global__ __launch_bounds__(256) void k_xw(
    const float* __restrict__ CW, const float* __restrict__ emb,
    const float* __restrict__ VW, const float* __restrict__ WQT4,
    const float* __restrict__ b_ih, const float* __restrict__ b_hh,
    float* __restrict__ XW4){
  int base = blockIdx.x * XR;
  int j = threadIdx.x;
  __shared__ float scw[XR][32];
  __shared__ __align__(16) float ses[XR][QDIM];
  for (int idx = j; idx < XR*32; idx += 256) {
    int r = idx >> 5, m = idx & 31, n = base + r;
    scw[r][m] = (n < NROWS) ? CW[n*256 + m] : 0.f;
  }
  for (int idx = j; idx < XR*QDIM; idx += 256) {
    int r = idx >> 7, d = idx & 127, n = base + r;
    ses[r][d] = (n < NROWS) ? emb[n*QDIM + d] : 0.f;
  }
  __syncthreads();
  float bias = b_ih[j] + b_hh[j];
  float acc[XR];
  #pragma unroll
  for (int r = 0; r < XR; ++r) acc[r] = bias;
  for (int m = 0; m < MM; ++m) {
    float wv = VW[m*256 + j];
    #pragma unroll
    for (int r = 0; r < XR; ++r) acc[r] += scw[r][m] * wv;
  }
  for (int d4 = 0; d4 < QDIM/4; ++d4) {
    float4 wq = *(const float4*)(WQT4 + d4*1024 + j*4);
    #pragma unroll
    for (int r = 0; r < XR; ++r) {
      float4 ev = *(const float4*)(&ses[r][4*d4]);
      acc[r] += ev.x*wq.x + ev.y*wq.y + ev.z*wq.z + ev.w*wq.w;
    }
  }
  int gate = j >> 6, unit = j & 63;
  #pragma unroll
  for (int r = 0; r < XR; ++r)
    if (base + r < NROWS) XW4[(size_t)(base + r)*256 + 4*unit + gate] = acc[r];
}

__global__ __launch_bounds__(1024) void k_dedup(
    const u32* __restrict__ present, const u64* __restrict__ KEYT,
    u32* __restrict__ g_htab, u32* __restrict__ g_pay,
    u32* __restrict__ counter, u64* __restrict__ uniq){
  __shared__ u32 sh_tab[DHS];
  __shared__ u32 sh_pay[DHS];
  __shared__ u32 sh_cnt;
  int tid = threadIdx.x;
  for (int i = tid; i < DHS; i += 1024) sh_tab[i] = 0u;
  if (tid == 0) sh_cnt = 0u;
  __syncthreads();
  for (int n = tid; n < NROWS; n += 1024) {
    if (present[n] != 1u) continue;
    u64 key = KEYT[n];
    u32 h = hash64(key) & DHMASK;
    while (true) {
      u32 cur = sh_tab[h];
      if (cur != 0u) {
        if (KEYT[cur-1u] == key) break;
        h = (h + 1) & DHMASK; continue;
      }
      u32 prev = atomicCAS(&sh_tab[h], 0u, (u32)(n + 1));
      if (prev == 0u) {
        u32 idx = atomicAdd(&sh_cnt, 1u);
        uniq[idx] = key;
        sh_pay[h] = idx;
        break;
      }
      if (KEYT[prev-1u] == key) break;
      h = (h + 1) & DHMASK;
    }
  }
  __syncthreads();
  for (int i = tid; i < DHS; i += 1024) {
    u32 v = sh_tab[i];
    g_htab[i] = v;
    g_pay[i]  = v ? sh_pay[i] : 0u;
  }
  if (tid == 0) *counter = sh_cnt;
}

__global__ __launch_bounds__(256) void k_rank(const u64* __restrict__ uniq,
                                              const u32* __restrict__ counter,
                                              u32* __restrict__ RANK){
  __shared__ u64 chunk[2048];
  u32 U = *counter;
  int u = blockIdx.x*256 + threadIdx.x;
  u64 mykey = (u < (int)U) ? uniq[u] : 0;
  u32 cnt = 0;
  for (u32 base = 0; base < U; base += 2048) {
    u32 n = (U - base < 2048u) ? (U - base) : 2048u;
    __syncthreads();
    for (u32 t = threadIdx.x; t < n; t += 256) chunk[t] = uniq[base + t];
    __syncthreads();
    if (u < (int)U)
      for (u32 j = 0; j < n; ++j) cnt += (chunk[j] < mykey) ? 1u : 0u;
  }
  if (u < (int)U) RANK[u] = cnt;
}

__global__ void k_qrank(const u32* __restrict__ present, const u64* __restrict__ KEYT,
                        const u32* __restrict__ g_htab, const u32* __restrict__ g_pay,
                        const u32* __restrict__ RANK, u32* __restrict__ RANKQ){
  int n = blockIdx.x*blockDim.x + threadIdx.x;
  if (n >= NROWS || present[n] != 1u) return;
  u64 key = KEYT[n];
  u32 h = hash64(key) & DHMASK;
  while (true) {
    u32 cur = g_htab[h];
    if (cur != 0u && KEYT[cur-1u] == key) { RANKQ[n] = RANK[g_pay[h]]; return; }
    h = (h + 1) & DHMASK;
  }
}

__global__ void k_ids(const int* __restrict__ q_data, const u32* __restrict__ RANKQ,
                      float* __restrict__ out_ids){
  int i = blockIdx.x*blockDim.x + threadIdx.x;
  if (i >= NSAMP) return;
  out_ids[i] = (float)RANKQ[clampq(q_data[i])];
}

// 16 sequential FMAs (one dep chain); 4 gates interleave for ILP
#define DOT16(acc, W, H) do { \
  acc += (W)[0]*(H)[0];   acc += (W)[1]*(H)[1];   acc += (W)[2]*(H)[2];   acc += (W)[3]*(H)[3]; \
  acc += (W)[4]*(H)[4];   acc += (W)[5]*(H)[5];   acc += (W)[6]*(H)[6];   acc += (W)[7]*(H)[7]; \
  acc += (W)[8]*(H)[8];   acc += (W)[9]*(H)[9];   acc += (W)[10]*(H)[10]; acc += (W)[11]*(H)[11]; \
  acc += (W)[12]*(H)[12]; acc += (W)[13]*(H)[13]; acc += (W)[14]*(H)[14]; acc += (W)[15]*(H)[15]; \
} while(0)

// LSTM v7: 4 waves, 2-D split. v6 post-mortem: VGPR_Count=132 < the ~200 live
// floats the design needed -> RA STILL remat'd W loads in-loop (L2 refetch ~=
// the 950 stall cyc/step). The allocator demonstrably gives ~132 regs, so this
// design fits UNDER it: wave w owns units [16w,16w+16); lane = (uo=l&15 unit,
// k=l>>4 h-chunk). Per lane: 4 gate rows x 16-wide h-chunk = 64 W VGPRs + 16 H
// + misc ~= 110 live. Partial-sum exchange = intra-wave shfl_xor butterfly
// (PART LDS buffer + its bank conflicts deleted); one barrier/step for the
// h-chunk exchange through Hbuf. Butterfly assoc (p0+p1)+(p2+p3) == v6's sum
// bit-exactly (commutativity covers lane-permuted forms).
__global__ __launch_bounds__(256, 1) void k_lstm(
    const int* __restrict__ q_data, const float* __restrict__ XW4,
    const float* __restrict__ W_hh,
    const float* __restrict__ W_pred, const float* __restrict__ b_pred,
    const float* __restrict__ init_h, const float* __restrict__ init_c,
    float* __restrict__ out_pred){
  const int b = blockIdx.x;
  const int t = threadIdx.x;
  const int w = t >> 6, l = t & 63;
  const int uo = l & 15, k = l >> 4;            // unit-offset, h-chunk
  const int u = 16*w + uo;                      // unit this lane computes
  __shared__ __align__(64) float Hbuf[SS][64];  // h history; 256B rows
  __shared__ int   sq[SS];
  __shared__ float swp[HH];

  for (int s = t; s < SS; s += 256) sq[s] = clampq(q_data[b*SS + s]);
  if (t < HH) swp[t] = W_pred[t];

  // W_hh rows for unit u, 4 gates, columns [16k,16k+16). Row stride 256B,
  // chunk offset 64B*k -> 64B-aligned f16v loads.
  const float* wb = W_hh + (size_t)u*HH + 16*k;
  f16v Wi = *(const f16v*)(wb +     0);
  f16v Wf = *(const f16v*)(wb +  4096);
  f16v Wg = *(const f16v*)(wb +  8192);
  f16v Wo = *(const f16v*)(wb + 12288);

  // this lane's h-chunk (replicated across the 16 uo-lanes sharing k)
  f16v H = *(const f16v*)(init_h + (size_t)b*HH + 16*k);
  float c  = init_c[b*HH + u];                  // 4 k-copies track c[u] redundantly
  float bp = b_pred[0];
  __syncthreads();

  // depth-2 XW prefetch (4 k-copies load the same float4: L1-hit, harmless)
  float4 xwA = *(const float4*)(XW4 + (size_t)sq[0]*256 + 4*u);
  float4 xwB = *(const float4*)(XW4 + (size_t)sq[1]*256 + 4*u);

  for (int s = 0; s < SS; ++s) {
    int sp = (s + 2 < SS) ? s + 2 : SS - 1;
    float4 xwC = *(const float4*)(XW4 + (size_t)sq[sp]*256 + 4*u);
    float pi=0.f, pf=0.f, pg=0.f, po=0.f;
    DOT16(pi, Wi, H); DOT16(pf, Wf, H); DOT16(pg, Wg, H); DOT16(po, Wo, H);
    // butterfly over k (lanes u,u+16,u+32,u+48 share a unit): (p0+p1)+(p2+p3)
    pi += __shfl_xor(pi, 16, 64); pf += __shfl_xor(pf, 16, 64);
    pg += __shfl_xor(pg, 16, 64); po += __shfl_xor(po, 16, 64);
    pi += __shfl_xor(pi, 32, 64); pf += __shfl_xor(pf, 32, 64);
    pg += __shfl_xor(pg, 32, 64); po += __shfl_xor(po, 32, 64);
    float ai = xwA.x + pi;
    float af = xwA.y + pf;
    float ag = xwA.z + pg;
    float ao = xwA.w + po;
    c = fsigm(af)*c + fsigm(ai)*ftanh(ag);
    float hh = fsigm(ao)*ftanh(c);
    if (l < 16) Hbuf[s][u] = hh;                // k==0 copies write wave's 16 units
    __syncthreads();                            // one cross-wave sync per step
    H = *(const f16v*)(&Hbuf[s][16*k]);         // per-k 64B read: broadcast + 2-way
    xwA = xwB; xwB = xwC;
  }
  __syncthreads();

  // pred epilogue over full Hbuf
  for (int s = t; s < SS; s += 256) {
    float acc = 0.f;
    #pragma unroll 16
    for (int kk = 0; kk < HH; ++kk) {
      int k2 = (kk + t) & 63;                   // swizzle: <=2-way banks (free)
      acc += Hbuf[s][k2] * swp[k2];
    }
    out_pred[b*SS + s] = fsigm(acc + bp);
  }
}

extern "C" void kernel_launch(void* const* d_in, const int* in_sizes, int n_in,
                              void* d_out, int out_size, void* d_ws, size_t ws_size,
                              hipStream_t stream) {
  const int*   q_data  = (const int*)d_in[0];
  const float* emb     = (const float*)d_in[1];
  const float* keym    = (const float*)d_in[2];
  const float* val     = (const float*)d_in[3];
  const float* W_ih    = (const float*)d_in[4];
  const float* W_hh    = (const float*)d_in[5];
  const float* b_ih    = (const float*)d_in[6];
  const float* b_hh    = (const float*)d_in[7];
  const float* W_pred  = (const float*)d_in[8];
  const float* b_pred  = (const float*)d_in[9];
  const float* init_h  = (const float*)d_in[10];
  const float* init_c  = (const float*)d_in[11];

  char* ws = (char*)d_ws;
  float* XW4     = (float*)(ws + 0);          // 10,241,024 (CW overlaid low 32 floats/row)
  float* VW      = (float*)(ws + 10241024);   // 32,768
  u64*  KEYT     = (u64*) (ws + 10273792);    // 80,128
  u64*  uniq     = (u64*) (ws + 10353920);    // 80,128
  u32*  RANK     = (u32*) (ws + 10434048);    // 40,192
  u32*  g_htab   = (u32*) (ws + 10474240);    // 32,768
  u32*  g_pay    = (u32*) (ws + 10507008);    // 32,768
  u32*  counter  = (u32*) (ws + 10539776);    // 64
  u32*  present  = (u32*) (ws + 10539840);    // 40,064
  u32*  RANKQ    = (u32*) (ws + 10579904);    // 40,064
  float* WQT4    = (float*)(ws + 10619968);   // 524,288
  float* KT      = (float*)(ws + 11144256);   // 16,384
  float* WVT     = (float*)(ws + 11160640);   // 262,144
  float* CW      = XW4;                       // overlay: CW[n*256+m]

  float* out_pred = (float*)d_out;
  float* out_ids  = out_pred + NSAMP;

  hipLaunchKernelGGL(k_tr,    dim3(824), dim3(256), 0, stream,
                     W_ih, keym, WQT4, KT, WVT, present);
  hipLaunchKernelGGL(k_front, dim3(NB_ATTN + MM + 200), dim3(256), 0, stream,
                     emb, KT, val, WVT, q_data, CW, KEYT, VW, present);
  hipLaunchKernelGGL(k_dedup, dim3(1), dim3(1024), 0, stream,
                     present, KEYT, g_htab, g_pay, counter, uniq);
  hipLaunchKernelGGL(k_rank,  dim3((NROWS+255)/256), dim3(256), 0, stream, uniq, counter, RANK);
  hipLaunchKernelGGL(k_qrank, dim3((NROWS+255)/256), dim3(256), 0, stream,
                     present, KEYT, g_htab, g_pay, RANK, RANKQ);
  hipLaunchKernelGGL(k_xw,    dim3((NROWS+XR-1)/XR), dim3(256), 0, stream,
                     CW, emb, VW, WQT4, b_ih, b_hh, XW4);
  hipLaunchKernelGGL(k_ids,   dim3((NSAMP+255)/256), dim3(256), 0, stream, q_data, RANKQ, out_ids);
  hipLaunchKernelGGL(k_lstm,  dim3(BB), dim3(256), 0, stream,
                     q_data, XW4, W_hh, W_pred, b_pred, init_h, init_c, out_pred);
}

// Round 5
// 236.545 us; speedup vs baseline: 1.5361x; 1.0135x over previous
//
#include <hip/hip_runtime.h>

#define BB 256
#define SS 200
#define MM 32
#define KDIM 128
#define VDIM 256
#define QDIM 128
#define HH 64
#define NROWS 10001
#define NSAMP (BB*SS)
#define INDIM (VDIM+QDIM)
#define DHS 8192
#define DHMASK (DHS-1)
#define XR 16
#define NB_ATTN 2501

typedef unsigned long long u64;
typedef unsigned int u32;
typedef float f16v __attribute__((ext_vector_type(16)));

__device__ __forceinline__ float fexp(float x){ return __builtin_amdgcn_exp2f(x * 1.44269504f); }
__device__ __forceinline__ float fsigm(float x){ return __builtin_amdgcn_rcpf(1.f + fexp(-x)); }
__device__ __forceinline__ float ftanh(float x){ return 1.f - 2.f*__builtin_amdgcn_rcpf(1.f + fexp(2.f*x)); }
__device__ __forceinline__ int clampq(int q){ return q < 0 ? 0 : (q > NROWS-1 ? NROWS-1 : q); }

__device__ __forceinline__ u32 hash64(u64 x){
  x ^= x >> 33; x *= 0xff51afd7ed558ccdULL;
  x ^= x >> 33; x *= 0xc4ceb9fe1a85ec53ULL;
  x ^= x >> 33;
  return (u32)x;
}

__device__ __forceinline__ u64 shflx64(u64 v, int m){
  int lo = __shfl_xor((int)(u32)v, m, 64);
  int hi = __shfl_xor((int)(u32)(v >> 32), m, 64);
  return ((u64)(u32)hi << 32) | (u32)lo;
}

// transposes + present init:
// WQT4[(d4*256+j)*4+dd]=W_ih[j][VDIM+4d4+dd]; KT[d*32+m]=key_mem[m][d];
// WVT[v*256+j]=W_ih[j][v]; present[:]=0
__global__ void k_tr(const float* __restrict__ W_ih, const float* __restrict__ key_mem,
                     float* __restrict__ WQT4, float* __restrict__ KT,
                     float* __restrict__ WVT, u32* __restrict__ present){
  int idx = blockIdx.x*256 + threadIdx.x;
  if (idx < 131072) {
    int dd = idx & 3, j = (idx >> 2) & 255, d4 = idx >> 10;
    WQT4[idx] = W_ih[j*INDIM + VDIM + 4*d4 + dd];
  } else if (idx < 135168) {
    int t = idx - 131072;
    int m = t & 31, d = t >> 5; KT[t] = key_mem[m*KDIM + d];
  } else if (idx < 200704) {
    int t = idx - 135168;
    int j = t & 255, v = t >> 8; WVT[v*256 + j] = W_ih[j*INDIM + v];
  } else {
    int t = idx - 200704;
    if (t < NROWS) present[t] = 0u;
  }
}

// fused front: blocks [0,2501) attn ; [2501,2533) vw ; [2533,2733) mark
__global__ __launch_bounds__(256) void k_front(
    const float* __restrict__ emb, const float* __restrict__ KT,
    const float* __restrict__ val, const float* __restrict__ WVT,
    const int* __restrict__ q_data,
    float* __restrict__ CW, u64* __restrict__ KEYT,
    float* __restrict__ VW, u32* __restrict__ present){
  int bid = blockIdx.x;
  if (bid < NB_ATTN) {
    // ---- attn: one wave per row ----
    int w = threadIdx.x >> 6, l = threadIdx.x & 63;
    int n = bid*4 + w;
    __shared__ float se[4][QDIM];
    bool valid = (n < NROWS);
    if (valid) {
      se[w][l]      = emb[n*QDIM + l];
      se[w][l + 64] = emb[n*QDIM + l + 64];
    }
    __syncthreads();
    int m = l & 31;
    float logit = 0.f;
    if (valid && l < 32)
      for (int d = 0; d < KDIM; ++d) logit += se[w][d] * KT[d*32 + m];
    float mx = logit;
    #pragma unroll
    for (int msk = 16; msk >= 1; msk >>= 1) mx = fmaxf(mx, __shfl_xor(mx, msk, 64));
    float e = (l < 32) ? expf(logit - mx) : 0.f;    // precise expf: trit boundaries
    float sum = e;
    #pragma unroll
    for (int msk = 16; msk >= 1; msk >>= 1) sum += __shfl_xor(sum, msk, 64);
    float cw = e / sum;
    float wv = fminf((cw - 0.075f)/0.013f, (1.0f - cw)/0.912f);
    wv = fmaxf(wv, 0.f);
    int iv = (wv >= 0.6f) ? 2 : ((wv >= 0.1f) ? 1 : 0);
    int ee = (m < 16) ? m + 16 : m - 16;   // key = kh*3^16 + kl (reference packing)
    u64 p3 = 1;
    for (int i = 0; i < 31; ++i) if (i < ee) p3 *= 3ULL;
    u64 term = (valid && l < 32) ? (u64)iv * p3 : 0ULL;
    #pragma unroll
    for (int msk = 16; msk >= 1; msk >>= 1) term += shflx64(term, msk);
    if (valid && l < 32) CW[n*256 + m] = cw;
    if (valid && l == 0) KEYT[n] = term;
  } else if (bid < NB_ATTN + MM) {
    // ---- vw: VW[m][j] = sum_v val[m][v]*WVT[v][j] ----
    int m = bid - NB_ATTN, j = threadIdx.x;
    __shared__ float sval[VDIM];
    sval[j] = val[m*VDIM + j];
    __syncthreads();
    float a0=0.f, a1=0.f, a2=0.f, a3=0.f;
    for (int v = 0; v < VDIM; v += 4) {
      a0 += sval[v+0]*WVT[(v+0)*256 + j];
      a1 += sval[v+1]*WVT[(v+1)*256 + j];
      a2 += sval[v+2]*WVT[(v+2)*256 + j];
      a3 += sval[v+3]*WVT[(v+3)*256 + j];
    }
    VW[m*256 + j] = (a0+a1)+(a2+a3);
  } else {
    // ---- mark ----
    int i = (bid - NB_ATTN - MM)*256 + threadIdx.x;
    if (i < NSAMP) present[clampq(q_data[i])] = 1u;
  }
}

// XW4 row = bias + cw.VW + emb.WqT: 16 rows/block tiled GEMM
__global__ __launch_bounds__(256) void k_xw(
    const float* __restrict__ CW, const float* __restrict__ emb,
    const float* __restrict__ VW, const float* __restrict__ WQT4,
    const float* __restrict__ b_ih, const float* __restrict__ b_hh,
    float* __restrict__ XW4){
  int base = blockIdx.x * XR;
  int j = threadIdx.x;
  __shared__ float scw[XR][32];
  __shared__ __align__(16) float ses[XR][QDIM];
  for (int idx = j; idx < XR*32; idx += 256) {
    int r = idx >> 5, m = idx & 31, n = base + r;
    scw[r][m] = (n < NROWS) ? CW[n*256 + m] : 0.f;
  }
  for (int idx = j; idx < XR*QDIM; idx += 256) {
    int r = idx >> 7, d = idx & 127, n = base + r;
    ses[r][d] = (n < NROWS) ? emb[n*QDIM + d] : 0.f;
  }
  __syncthreads();
  float bias = b_ih[j] + b_hh[j];
  float acc[XR];
  #pragma unroll
  for (int r = 0; r < XR; ++r) acc[r] = bias;
  for (int m = 0; m < MM; ++m) {
    float wv = VW[m*256 + j];
    #pragma unroll
    for (int r = 0; r < XR; ++r) acc[r] += scw[r][m] * wv;
  }
  for (int d4 = 0; d4 < QDIM/4; ++d4) {
    float4 wq = *(const float4*)(WQT4 + d4*1024 + j*4);
    #pragma unroll
    for (int r = 0; r < XR; ++r) {
      float4 ev = *(const float4*)(&ses[r][4*d4]);
      acc[r] += ev.x*wq.x + ev.y*wq.y + ev.z*wq.z + ev.w*wq.w;
    }
  }
  int gate = j >> 6, unit = j & 63;
  #pragma unroll
  for (int r = 0; r < XR; ++r)
    if (base + r < NROWS) XW4[(size_t)(base + r)*256 + 4*unit + gate] = acc[r];
}

__global__ __launch_bounds__(1024) void k_dedup(
    const u32* __restrict__ present, const u64* __restrict__ KEYT,
    u32* __restrict__ g_htab, u32* __restrict__ g_pay,
    u32* __restrict__ counter, u64* __restrict__ uniq){
  __shared__ u32 sh_tab[DHS];
  __shared__ u32 sh_pay[DHS];
  __shared__ u32 sh_cnt;
  int tid = threadIdx.x;
  for (int i = tid; i < DHS; i += 1024) sh_tab[i] = 0u;
  if (tid == 0) sh_cnt = 0u;
  __syncthreads();
  for (int n = tid; n < NROWS; n += 1024) {
    if (present[n] != 1u) continue;
    u64 key = KEYT[n];
    u32 h = hash64(key) & DHMASK;
    while (true) {
      u32 cur = sh_tab[h];
      if (cur != 0u) {
        if (KEYT[cur-1u] == key) break;
        h = (h + 1) & DHMASK; continue;
      }
      u32 prev = atomicCAS(&sh_tab[h], 0u, (u32)(n + 1));
      if (prev == 0u) {
        u32 idx = atomicAdd(&sh_cnt, 1u);
        uniq[idx] = key;
        sh_pay[h] = idx;
        break;
      }
      if (KEYT[prev-1u] == key) break;
      h = (h + 1) & DHMASK;
    }
  }
  __syncthreads();
  for (int i = tid; i < DHS; i += 1024) {
    u32 v = sh_tab[i];
    g_htab[i] = v;
    g_pay[i]  = v ? sh_pay[i] : 0u;
  }
  if (tid == 0) *counter = sh_cnt;
}

__global__ __launch_bounds__(256) void k_rank(const u64* __restrict__ uniq,
                                              const u32* __restrict__ counter,
                                              u32* __restrict__ RANK){
  __shared__ u64 chunk[2048];
  u32 U = *counter;
  int u = blockIdx.x*256 + threadIdx.x;
  u64 mykey = (u < (int)U) ? uniq[u] : 0;
  u32 cnt = 0;
  for (u32 base = 0; base < U; base += 2048) {
    u32 n = (U - base < 2048u) ? (U - base) : 2048u;
    __syncthreads();
    for (u32 t = threadIdx.x; t < n; t += 256) chunk[t] = uniq[base + t];
    __syncthreads();
    if (u < (int)U)
      for (u32 j = 0; j < n; ++j) cnt += (chunk[j] < mykey) ? 1u : 0u;
  }
  if (u < (int)U) RANK[u] = cnt;
}

__global__ void k_qrank(const u32* __restrict__ present, const u64* __restrict__ KEYT,
                        const u32* __restrict__ g_htab, const u32* __restrict__ g_pay,
                        const u32* __restrict__ RANK, u32* __restrict__ RANKQ){
  int n = blockIdx.x*blockDim.x + threadIdx.x;
  if (n >= NROWS || present[n] != 1u) return;
  u64 key = KEYT[n];
  u32 h = hash64(key) & DHMASK;
  while (true) {
    u32 cur = g_htab[h];
    if (cur != 0u && KEYT[cur-1u] == key) { RANKQ[n] = RANK[g_pay[h]]; return; }
    h = (h + 1) & DHMASK;
  }
}

__global__ void k_ids(const int* __restrict__ q_data, const u32* __restrict__ RANKQ,
                      float* __restrict__ out_ids){
  int i = blockIdx.x*blockDim.x + threadIdx.x;
  if (i >= NSAMP) return;
  out_ids[i] = (float)RANKQ[clampq(q_data[i])];
}

// one gate's 16-FMA chain from 4 pinned float4s; SAME order/assoc as v7's DOT16
#define DOTG(acc, w0, w1, w2, w3, H) do { \
  acc += (w0).x*(H)[0];  acc += (w0).y*(H)[1];  acc += (w0).z*(H)[2];  acc += (w0).w*(H)[3]; \
  acc += (w1).x*(H)[4];  acc += (w1).y*(H)[5];  acc += (w1).z*(H)[6];  acc += (w1).w*(H)[7]; \
  acc += (w2).x*(H)[8];  acc += (w2).y*(H)[9];  acc += (w2).z*(H)[10]; acc += (w2).w*(H)[11]; \
  acc += (w3).x*(H)[12]; acc += (w3).y*(H)[13]; acc += (w3).z*(H)[14]; acc += (w3).w*(H)[15]; \
} while(0)

// opaque-register pin: value becomes asm-defined -> backend CANNOT remat it by
// re-executing the load (only keep-in-VGPR or spill; at ~130 live vs 256 cap it keeps)
#define PINV(v4) asm volatile("" : "+v"((v4).x), "+v"((v4).y), "+v"((v4).z), "+v"((v4).w))

// LSTM v8: v7 structure + pinned W. v7 post-mortem: VGPR_Count=68 (< the 80
// needed just for W+H) proved the backend AGAIN sank the loop-invariant W
// loads in-loop -- 4 waves re-read all 64KB of W_hh per CU per step ~= 1100
// cyc/step = the whole gap (observed 1162 cyc/step, VALU 42.6%). launch_bounds
// min-waves is only a floor; the scheduler's occupancy heuristic keeps choosing
// reload-over-residency. The empty-asm pin (guide rule #17) removes that choice.
__global__ __launch_bounds__(256, 1) void k_lstm(
    const int* __restrict__ q_data, const float* __restrict__ XW4,
    const float* __restrict__ W_hh,
    const float* __restrict__ W_pred, const float* __restrict__ b_pred,
    const float* __restrict__ init_h, const float* __restrict__ init_c,
    float* __restrict__ out_pred){
  const int b = blockIdx.x;
  const int t = threadIdx.x;
  const int w = t >> 6, l = t & 63;
  const int uo = l & 15, k = l >> 4;            // unit-offset, h-chunk
  const int u = 16*w + uo;                      // unit this lane computes
  __shared__ __align__(64) float Hbuf[SS][64];  // h history; 256B rows
  __shared__ int   sq[SS];
  __shared__ float swp[HH];

  for (int s = t; s < SS; s += 256) sq[s] = clampq(q_data[b*SS + s]);
  if (t < HH) swp[t] = W_pred[t];

  // W_hh rows for unit u, 4 gates, columns [16k,16k+16). Row stride 256B,
  // chunk offset 64B*k -> aligned float4 loads. 16 float4 = 64 VGPRs.
  const float* wb = W_hh + (size_t)u*HH + 16*k;
  float4 wi0 = *(const float4*)(wb +     0), wi1 = *(const float4*)(wb +     4);
  float4 wi2 = *(const float4*)(wb +     8), wi3 = *(const float4*)(wb +    12);
  float4 wf0 = *(const float4*)(wb +  4096), wf1 = *(const float4*)(wb +  4100);
  float4 wf2 = *(const float4*)(wb +  4104), wf3 = *(const float4*)(wb +  4108);
  float4 wg0 = *(const float4*)(wb +  8192), wg1 = *(const float4*)(wb +  8196);
  float4 wg2 = *(const float4*)(wb +  8200), wg3 = *(const float4*)(wb +  8204);
  float4 wo0 = *(const float4*)(wb + 12288), wo1 = *(const float4*)(wb + 12292);
  float4 wo2 = *(const float4*)(wb + 12296), wo3 = *(const float4*)(wb + 12300);
  PINV(wi0); PINV(wi1); PINV(wi2); PINV(wi3);
  PINV(wf0); PINV(wf1); PINV(wf2); PINV(wf3);
  PINV(wg0); PINV(wg1); PINV(wg2); PINV(wg3);
  PINV(wo0); PINV(wo1); PINV(wo2); PINV(wo3);

  // this lane's h-chunk (replicated across the 16 uo-lanes sharing k)
  f16v H = *(const f16v*)(init_h + (size_t)b*HH + 16*k);
  float c  = init_c[b*HH + u];                  // 4 k-copies track c[u] redundantly
  float bp = b_pred[0];
  __syncthreads();

  // depth-2 XW prefetch (4 k-copies load the same float4: L1-hit, harmless)
  float4 xwA = *(const float4*)(XW4 + (size_t)sq[0]*256 + 4*u);
  float4 xwB = *(const float4*)(XW4 + (size_t)sq[1]*256 + 4*u);

  for (int s = 0; s < SS; ++s) {
    int sp = (s + 2 < SS) ? s + 2 : SS - 1;
    float4 xwC = *(const float4*)(XW4 + (size_t)sq[sp]*256 + 4*u);
    float pi=0.f, pf=0.f, pg=0.f, po=0.f;
    DOTG(pi, wi0, wi1, wi2, wi3, H);
    DOTG(pf, wf0, wf1, wf2, wf3, H);
    DOTG(pg, wg0, wg1, wg2, wg3, H);
    DOTG(po, wo0, wo1, wo2, wo3, H);
    // butterfly over k (lanes u,u+16,u+32,u+48 share a unit): (p0+p1)+(p2+p3)
    pi += __shfl_xor(pi, 16, 64); pf += __shfl_xor(pf, 16, 64);
    pg += __shfl_xor(pg, 16, 64); po += __shfl_xor(po, 16, 64);
    pi += __shfl_xor(pi, 32, 64); pf += __shfl_xor(pf, 32, 64);
    pg += __shfl_xor(pg, 32, 64); po += __shfl_xor(po, 32, 64);
    float ai = xwA.x + pi;
    float af = xwA.y + pf;
    float ag = xwA.z + pg;
    float ao = xwA.w + po;
    c = fsigm(af)*c + fsigm(ai)*ftanh(ag);
    float hh = fsigm(ao)*ftanh(c);
    if (l < 16) Hbuf[s][u] = hh;                // k==0 copies write wave's 16 units
    __syncthreads();                            // one cross-wave sync per step
    H = *(const f16v*)(&Hbuf[s][16*k]);         // per-k 64B read: broadcast + 2-way
    xwA = xwB; xwB = xwC;
  }
  __syncthreads();

  // pred epilogue over full Hbuf
  for (int s = t; s < SS; s += 256) {
    float acc = 0.f;
    #pragma unroll 16
    for (int kk = 0; kk < HH; ++kk) {
      int k2 = (kk + t) & 63;                   // swizzle: <=2-way banks (free)
      acc += Hbuf[s][k2] * swp[k2];
    }
    out_pred[b*SS + s] = fsigm(acc + bp);
  }
}

extern "C" void kernel_launch(void* const* d_in, const int* in_sizes, int n_in,
                              void* d_out, int out_size, void* d_ws, size_t ws_size,
                              hipStream_t stream) {
  const int*   q_data  = (const int*)d_in[0];
  const float* emb     = (const float*)d_in[1];
  const float* keym    = (const float*)d_in[2];
  const float* val     = (const float*)d_in[3];
  const float* W_ih    = (const float*)d_in[4];
  const float* W_hh    = (const float*)d_in[5];
  const float* b_ih    = (const float*)d_in[6];
  const float* b_hh    = (const float*)d_in[7];
  const float* W_pred  = (const float*)d_in[8];
  const float* b_pred  = (const float*)d_in[9];
  const float* init_h  = (const float*)d_in[10];
  const float* init_c  = (const float*)d_in[11];

  char* ws = (char*)d_ws;
  float* XW4     = (float*)(ws + 0);          // 10,241,024 (CW overlaid low 32 floats/row)
  float* VW      = (float*)(ws + 10241024);   // 32,768
  u64*  KEYT     = (u64*) (ws + 10273792);    // 80,128
  u64*  uniq     = (u64*) (ws + 10353920);    // 80,128
  u32*  RANK     = (u32*) (ws + 10434048);    // 40,192
  u32*  g_htab   = (u32*) (ws + 10474240);    // 32,768
  u32*  g_pay    = (u32*) (ws + 10507008);    // 32,768
  u32*  counter  = (u32*) (ws + 10539776);    // 64
  u32*  present  = (u32*) (ws + 10539840);    // 40,064
  u32*  RANKQ    = (u32*) (ws + 10579904);    // 40,064
  float* WQT4    = (float*)(ws + 10619968);   // 524,288
  float* KT      = (float*)(ws + 11144256);   // 16,384
  float* WVT     = (float*)(ws + 11160640);   // 262,144
  float* CW      = XW4;                       // overlay: CW[n*256+m]

  float* out_pred = (float*)d_out;
  float* out_ids  = out_pred + NSAMP;

  hipLaunchKernelGGL(k_tr,    dim3(824), dim3(256), 0, stream,
                     W_ih, keym, WQT4, KT, WVT, present);
  hipLaunchKernelGGL(k_front, dim3(NB_ATTN + MM + 200), dim3(256), 0, stream,
                     emb, KT, val, WVT, q_data, CW, KEYT, VW, present);
  hipLaunchKernelGGL(k_dedup, dim3(1), dim3(1024), 0, stream,
                     present, KEYT, g_htab, g_pay, counter, uniq);
  hipLaunchKernelGGL(k_rank,  dim3((NROWS+255)/256), dim3(256), 0, stream, uniq, counter, RANK);
  hipLaunchKernelGGL(k_qrank, dim3((NROWS+255)/256), dim3(256), 0, stream,
                     present, KEYT, g_htab, g_pay, RANK, RANKQ);
  hipLaunchKernelGGL(k_xw,    dim3((NROWS+XR-1)/XR), dim3(256), 0, stream,
                     CW, emb, VW, WQT4, b_ih, b_hh, XW4);
  hipLaunchKernelGGL(k_ids,   dim3((NSAMP+255)/256), dim3(256), 0, stream, q_data, RANKQ, out_ids);
  hipLaunchKernelGGL(k_lstm,  dim3(BB), dim3(256), 0, stream,
                     q_data, XW4, W_hh, W_pred, b_pred, init_h, init_c, out_pred);
}